// Round 2
// baseline (415.168 us; speedup 1.0000x reference)
//
#include <hip/hip_runtime.h>
#include <stdint.h>

typedef __bf16 bf16;
typedef bf16 bf16x8 __attribute__((ext_vector_type(8)));
typedef float f32x4 __attribute__((ext_vector_type(4)));
typedef unsigned short u16;
typedef unsigned int u32;
typedef u16 u16x4v __attribute__((ext_vector_type(4)));
typedef u16 u16x8v __attribute__((ext_vector_type(8)));

// RNE float -> bf16 bits
__device__ __forceinline__ u16 f2bf(float f) {
  u32 u = __float_as_uint(f);
  u32 r = u + 0x7fffu + ((u >> 16) & 1u);
  return (u16)(r >> 16);
}
__device__ __forceinline__ float bf2f(u16 h) {
  return __uint_as_float(((u32)h) << 16);
}

union ABu { u16x8v u; bf16x8 b; };

// ---- Kernel A: Wh/Wl[w][out][in] = split-bf16 of W_w[in][out] ----
__global__ void wt_kernel(const float* __restrict__ Wq, const float* __restrict__ Wk,
                          const float* __restrict__ Wv, u16* __restrict__ Wh,
                          u16* __restrict__ Wl) {
  int w = blockIdx.x >> 4;
  int chunk = blockIdx.x & 15;
  const float* W = (w == 0) ? Wq : (w == 1) ? Wk : Wv;
  int t = threadIdx.x;
  int o = chunk * 16 + (t & 15);
  int i0 = (t >> 4) * 16;
  u16x8v h0, h1, l0, l1;
  #pragma unroll
  for (int ii = 0; ii < 8; ++ii) {
    float v0 = W[(size_t)(i0 + ii) * 256 + o];
    u16 h = f2bf(v0); h0[ii] = h; l0[ii] = f2bf(v0 - bf2f(h));
    float v1 = W[(size_t)(i0 + 8 + ii) * 256 + o];
    h = f2bf(v1); h1[ii] = h; l1[ii] = f2bf(v1 - bf2f(h));
  }
  size_t base = (size_t)w * 65536 + (size_t)o * 256 + i0;
  *(u16x8v*)(Wh + base) = h0; *(u16x8v*)(Wh + base + 8) = h1;
  *(u16x8v*)(Wl + base) = l0; *(u16x8v*)(Wl + base + 8) = l1;
}

// ---- Kernel B: QKV projection, fp32-accurate via 3-pass split-bf16 MFMA ----
// grid (256,3). Q,K -> hi/lo bf16 row-major [16384][256]; V -> bf16 Vt[b][d][s].
__global__ __launch_bounds__(256) void proj_kernel(
    const float* __restrict__ x, const float* __restrict__ bq,
    const float* __restrict__ bk, const float* __restrict__ bv,
    const u16* __restrict__ Wh, const u16* __restrict__ Wl,
    u16* __restrict__ Qh, u16* __restrict__ Ql,
    u16* __restrict__ Kh, u16* __restrict__ Kl, u16* __restrict__ Vt) {
  int m = blockIdx.x, w = blockIdx.y;
  int tid = threadIdx.x, lane = tid & 63;
  int wv = tid >> 6;
  int r = lane & 15, c = lane >> 4;
  int row0 = m * 64 + wv * 16;
  const u16* Whw = Wh + (size_t)w * 65536;
  const u16* Wlw = Wl + (size_t)w * 65536;
  const float* bias = (w == 0) ? bq : (w == 1) ? bk : bv;

  f32x4 acc[16];
  #pragma unroll
  for (int n = 0; n < 16; ++n) acc[n] = (f32x4)0.0f;

  const float* xrow = x + (size_t)(row0 + r) * 256;
  #pragma unroll
  for (int ks = 0; ks < 8; ++ks) {
    float4 a0 = *(const float4*)(xrow + ks * 32 + c * 8);
    float4 a1 = *(const float4*)(xrow + ks * 32 + c * 8 + 4);
    ABu ah, al;
    float xv[8] = {a0.x, a0.y, a0.z, a0.w, a1.x, a1.y, a1.z, a1.w};
    #pragma unroll
    for (int j = 0; j < 8; ++j) {
      u16 h = f2bf(xv[j]);
      ah.u[j] = h;
      al.u[j] = f2bf(xv[j] - bf2f(h));
    }
    #pragma unroll
    for (int n = 0; n < 16; ++n) {
      size_t off = (size_t)(n * 16 + r) * 256 + ks * 32 + c * 8;
      bf16x8 whf = *(const bf16x8*)(Whw + off);
      bf16x8 wlf = *(const bf16x8*)(Wlw + off);
      acc[n] = __builtin_amdgcn_mfma_f32_16x16x32_bf16(ah.b, whf, acc[n], 0, 0, 0);
      acc[n] = __builtin_amdgcn_mfma_f32_16x16x32_bf16(al.b, whf, acc[n], 0, 0, 0);
      acc[n] = __builtin_amdgcn_mfma_f32_16x16x32_bf16(ah.b, wlf, acc[n], 0, 0, 0);
    }
  }

  if (w < 2) {
    u16* oh = (w == 0) ? Qh : Kh;
    u16* ol = (w == 0) ? Ql : Kl;
    #pragma unroll
    for (int n = 0; n < 16; ++n) {
      int col = n * 16 + r;
      float bb = bias[col];
      #pragma unroll
      for (int i = 0; i < 4; ++i) {
        float v = fmaxf(acc[n][i] + bb, 0.0f);
        u16 h = f2bf(v);
        size_t idx = (size_t)(row0 + c * 4 + i) * 256 + col;
        oh[idx] = h;
        ol[idx] = f2bf(v - bf2f(h));
      }
    }
  } else {
    int grow = row0 + c * 4;
    int b = grow >> 12, s0 = grow & 4095;
    #pragma unroll
    for (int n = 0; n < 16; ++n) {
      int d = n * 16 + r;
      float bb = bias[d];
      u16x4v pk;
      #pragma unroll
      for (int i = 0; i < 4; ++i) pk[i] = f2bf(acc[n][i] + bb);
      *(u16x4v*)(Vt + (size_t)(b * 256 + d) * 4096 + s0) = pk;
    }
  }
}

// ---- Kernel C: flash attention, 3-pass split-bf16 QK^T ----
// 256 blocks x 4 waves, 16 q-rows/wave, KV tile = 64 keys.
// Kh/Kl [64][256] + V^T [256][64] staged via global_load_lds
// (linear LDS dest, XOR-swizzled GLOBAL source; reads apply same XOR).
__global__ __launch_bounds__(256, 1) void attn_kernel(
    const u16* __restrict__ Qh, const u16* __restrict__ Ql,
    const u16* __restrict__ Kh, const u16* __restrict__ Kl,
    const u16* __restrict__ Vt, float* __restrict__ out) {
  __shared__ __align__(16) char Khs[32768];
  __shared__ __align__(16) char Kls[32768];
  __shared__ __align__(16) char Vsm[32768];
  __shared__ __align__(16) u16 Psm[4][16][80];   // per-wave P tile, 160B rows

  int L = blockIdx.x;
  int b = (L >> 1) & 3;                 // batch pinned to XCD pairs
  int qt = ((L >> 3) << 1) | (L & 1);
  int tid = threadIdx.x, lane = tid & 63, wv = tid >> 6;
  int r = lane & 15, c = lane >> 4;
  int q0 = qt * 64 + wv * 16;

  bf16x8 qh[8], ql[8];
  {
    const u16* qrh = Qh + (size_t)(b * 4096 + q0 + r) * 256;
    const u16* qrl = Ql + (size_t)(b * 4096 + q0 + r) * 256;
    #pragma unroll
    for (int ks = 0; ks < 8; ++ks) {
      qh[ks] = *(const bf16x8*)(qrh + ks * 32 + c * 8);
      ql[ks] = *(const bf16x8*)(qrl + ks * 32 + c * 8);
    }
  }

  f32x4 O[16];
  #pragma unroll
  for (int n = 0; n < 16; ++n) O[n] = (f32x4)0.0f;
  float mrow[4], lrow[4];
  #pragma unroll
  for (int i = 0; i < 4; ++i) { mrow[i] = -3.0e38f; lrow[i] = 0.0f; }

  const u16* Khb = Kh + (size_t)b * 4096 * 256;
  const u16* Klb = Kl + (size_t)b * 4096 * 256;
  const u16* Vtb = Vt + (size_t)b * 256 * 4096;
  int wavebase = (tid & ~63) << 4;  // wv*1024: wave-uniform LDS byte base per 4KB round

  for (int kv = 0; kv < 4096; kv += 64) {
    __syncthreads();
    // stage Kh, Kl tiles: 2048 slots x 16B each; slot -> row=slot>>5, chunk=slot&31
    #pragma unroll
    for (int rr = 0; rr < 8; ++rr) {
      int slot = rr * 256 + tid;
      int krow = slot >> 5;
      int dby = ((slot & 31) << 4) ^ ((krow & 7) << 4);
      const char* gh = (const char*)(Khb + (size_t)(kv + krow) * 256) + dby;
      const char* gl = (const char*)(Klb + (size_t)(kv + krow) * 256) + dby;
      __builtin_amdgcn_global_load_lds(
          (const __attribute__((address_space(1))) void*)gh,
          (__attribute__((address_space(3))) void*)(Khs + rr * 4096 + wavebase),
          16, 0, 0);
      __builtin_amdgcn_global_load_lds(
          (const __attribute__((address_space(1))) void*)gl,
          (__attribute__((address_space(3))) void*)(Kls + rr * 4096 + wavebase),
          16, 0, 0);
    }
    // stage V^T tile: rows are d (128B); slot -> row=slot>>3, chunk=slot&7
    #pragma unroll
    for (int rr = 0; rr < 8; ++rr) {
      int slot = rr * 256 + tid;
      int vrow = slot >> 3;
      int dby = ((slot & 7) << 4) ^ ((vrow & 7) << 4);
      const char* g = (const char*)(Vtb + (size_t)vrow * 4096 + kv) + dby;
      __builtin_amdgcn_global_load_lds(
          (const __attribute__((address_space(1))) void*)g,
          (__attribute__((address_space(3))) void*)(Vsm + rr * 4096 + wavebase),
          16, 0, 0);
    }
    __syncthreads();

    // S = Q K^T : 3-pass split (qh*kh + ql*kh + qh*kl)
    f32x4 sAcc[4];
    #pragma unroll
    for (int n = 0; n < 4; ++n) sAcc[n] = (f32x4)0.0f;
    #pragma unroll
    for (int ks = 0; ks < 8; ++ks) {
      #pragma unroll
      for (int n = 0; n < 4; ++n) {
        int krow = n * 16 + r;
        int dby = (ks * 64 + c * 16) ^ ((krow & 7) << 4);
        bf16x8 khf = *(const bf16x8*)(Khs + krow * 512 + dby);
        sAcc[n] = __builtin_amdgcn_mfma_f32_16x16x32_bf16(qh[ks], khf, sAcc[n], 0, 0, 0);
        sAcc[n] = __builtin_amdgcn_mfma_f32_16x16x32_bf16(ql[ks], khf, sAcc[n], 0, 0, 0);
        bf16x8 klf = *(const bf16x8*)(Kls + krow * 512 + dby);
        sAcc[n] = __builtin_amdgcn_mfma_f32_16x16x32_bf16(qh[ks], klf, sAcc[n], 0, 0, 0);
      }
    }

    // online softmax over keys (16-lane groups hold 16 keys each x 4 n-tiles)
    float tmax[4];
    #pragma unroll
    for (int i = 0; i < 4; ++i)
      tmax[i] = fmaxf(fmaxf(sAcc[0][i], sAcc[1][i]), fmaxf(sAcc[2][i], sAcc[3][i]));
    #pragma unroll
    for (int d = 1; d < 16; d <<= 1) {
      #pragma unroll
      for (int i = 0; i < 4; ++i) tmax[i] = fmaxf(tmax[i], __shfl_xor(tmax[i], d));
    }
    bool up = false;
    #pragma unroll
    for (int i = 0; i < 4; ++i) up = up || (tmax[i] > mrow[i]);
    if (__any(up)) {   // exact skip: only when no row max grew
      #pragma unroll
      for (int i = 0; i < 4; ++i) {
        float mn = fmaxf(mrow[i], tmax[i]);
        float sc = __expf(mrow[i] - mn);
        mrow[i] = mn;
        lrow[i] *= sc;
        #pragma unroll
        for (int n = 0; n < 16; ++n) O[n][i] *= sc;
      }
    }

    // P = exp(S - m) -> per-wave LDS (D-layout), accumulate row sums
    float psum[4] = {0.f, 0.f, 0.f, 0.f};
    #pragma unroll
    for (int n = 0; n < 4; ++n) {
      #pragma unroll
      for (int i = 0; i < 4; ++i) {
        float p = __expf(sAcc[n][i] - mrow[i]);
        psum[i] += p;
        Psm[wv][c * 4 + i][n * 16 + r] = f2bf(p);
      }
    }
    #pragma unroll
    for (int d = 1; d < 16; d <<= 1) {
      #pragma unroll
      for (int i = 0; i < 4; ++i) psum[i] += __shfl_xor(psum[i], d);
    }
    #pragma unroll
    for (int i = 0; i < 4; ++i) lrow[i] += psum[i];

    // O += P V
    #pragma unroll
    for (int ks2 = 0; ks2 < 2; ++ks2) {
      bf16x8 pf = *(const bf16x8*)(&Psm[wv][r][ks2 * 32 + c * 8]);
      #pragma unroll
      for (int n = 0; n < 16; ++n) {
        int vrow = n * 16 + r;
        int dby = (ks2 * 64 + c * 16) ^ ((vrow & 7) << 4);
        bf16x8 vf = *(const bf16x8*)(Vsm + vrow * 128 + dby);
        O[n] = __builtin_amdgcn_mfma_f32_16x16x32_bf16(pf, vf, O[n], 0, 0, 0);
      }
    }
  }

  float inv[4];
  #pragma unroll
  for (int i = 0; i < 4; ++i) inv[i] = 1.0f / lrow[i];
  #pragma unroll
  for (int n = 0; n < 16; ++n) {
    #pragma unroll
    for (int i = 0; i < 4; ++i)
      out[(size_t)(b * 4096 + q0 + c * 4 + i) * 256 + n * 16 + r] = O[n][i] * inv[i];
  }
}

extern "C" void kernel_launch(void* const* d_in, const int* in_sizes, int n_in,
                              void* d_out, int out_size, void* d_ws, size_t ws_size,
                              hipStream_t stream) {
  const float* x  = (const float*)d_in[0];
  const float* Wq = (const float*)d_in[1];
  const float* bq = (const float*)d_in[2];
  const float* Wk = (const float*)d_in[3];
  const float* bk = (const float*)d_in[4];
  const float* Wv = (const float*)d_in[5];
  const float* bv = (const float*)d_in[6];
  float* out = (float*)d_out;

  // ws (bf16 elems): Wh[3][256][256] | Wl[3][256][256] | Qh | Ql | Kh | Kl (each [16384][256]) | Vt[4][256][4096]
  u16* Wh = (u16*)d_ws;
  u16* Wl = Wh + 3 * 65536;
  u16* Qh = Wl + 3 * 65536;
  u16* Ql = Qh + (size_t)16384 * 256;
  u16* Kh = Ql + (size_t)16384 * 256;
  u16* Kl = Kh + (size_t)16384 * 256;
  u16* Vt = Kl + (size_t)16384 * 256;

  wt_kernel<<<48, 256, 0, stream>>>(Wq, Wk, Wv, Wh, Wl);
  proj_kernel<<<dim3(256, 3), 256, 0, stream>>>(x, bq, bk, bv, Wh, Wl, Qh, Ql, Kh, Kl, Vt);
  attn_kernel<<<256, 256, 0, stream>>>(Qh, Ql, Kh, Kl, Vt, out);
}

// Round 3
// 255.019 us; speedup vs baseline: 1.6280x; 1.6280x over previous
//
#include <hip/hip_runtime.h>
#include <stdint.h>

typedef __bf16 bf16;
typedef bf16 bf16x8 __attribute__((ext_vector_type(8)));
typedef _Float16 f16;
typedef f16 f16x8 __attribute__((ext_vector_type(8)));
typedef f16 f16x4 __attribute__((ext_vector_type(4)));
typedef float f32x4 __attribute__((ext_vector_type(4)));
typedef unsigned short u16;
typedef unsigned int u32;
typedef u16 u16x8v __attribute__((ext_vector_type(8)));

__device__ __forceinline__ u16 f2bf(float f) {
  u32 u = __float_as_uint(f);
  u32 r = u + 0x7fffu + ((u >> 16) & 1u);
  return (u16)(r >> 16);
}
__device__ __forceinline__ float bf2f(u16 h) { return __uint_as_float(((u32)h) << 16); }

union ABu { u16x8v u; bf16x8 b; };

// ---- Kernel A: Wh/Wl[w][out][in] = split-bf16 of W_w[in][out] ----
__global__ void wt_kernel(const float* __restrict__ Wq, const float* __restrict__ Wk,
                          const float* __restrict__ Wv, u16* __restrict__ Wh,
                          u16* __restrict__ Wl) {
  int w = blockIdx.x >> 4;
  int chunk = blockIdx.x & 15;
  const float* W = (w == 0) ? Wq : (w == 1) ? Wk : Wv;
  int t = threadIdx.x;
  int o = chunk * 16 + (t & 15);
  int i0 = (t >> 4) * 16;
  u16x8v h0, h1, l0, l1;
  #pragma unroll
  for (int ii = 0; ii < 8; ++ii) {
    float v0 = W[(size_t)(i0 + ii) * 256 + o];
    u16 h = f2bf(v0); h0[ii] = h; l0[ii] = f2bf(v0 - bf2f(h));
    float v1 = W[(size_t)(i0 + 8 + ii) * 256 + o];
    h = f2bf(v1); h1[ii] = h; l1[ii] = f2bf(v1 - bf2f(h));
  }
  size_t base = (size_t)w * 65536 + (size_t)o * 256 + i0;
  *(u16x8v*)(Wh + base) = h0; *(u16x8v*)(Wh + base + 8) = h1;
  *(u16x8v*)(Wl + base) = l0; *(u16x8v*)(Wl + base + 8) = l1;
}

// ---- Kernel B: QKV projection (fp32-exact 3-pass bf16), outputs f16 ----
// grid (128, 3): 128-row tiles, 4 waves x 32 rows (2 groups of 16).
__global__ __launch_bounds__(256, 2) void proj_kernel(
    const float* __restrict__ x, const float* __restrict__ bq,
    const float* __restrict__ bk, const float* __restrict__ bv,
    const u16* __restrict__ Wh, const u16* __restrict__ Wl,
    f16* __restrict__ Qf, f16* __restrict__ Kf, f16* __restrict__ Vt) {
  int m = blockIdx.x, w = blockIdx.y;
  int tid = threadIdx.x, lane = tid & 63, wv = tid >> 6;
  int r = lane & 15, c = lane >> 4;
  int row0 = m * 128 + wv * 32;
  const u16* Whw = Wh + (size_t)w * 65536;
  const u16* Wlw = Wl + (size_t)w * 65536;
  const float* bias = (w == 0) ? bq : (w == 1) ? bk : bv;

  f32x4 acc[2][16];
  #pragma unroll
  for (int g = 0; g < 2; ++g)
    #pragma unroll
    for (int n = 0; n < 16; ++n) acc[g][n] = (f32x4)0.0f;

  #pragma unroll
  for (int ks = 0; ks < 8; ++ks) {
    ABu ah[2], al[2];
    #pragma unroll
    for (int g = 0; g < 2; ++g) {
      const float* xrow = x + (size_t)(row0 + g * 16 + r) * 256 + ks * 32 + c * 8;
      float4 a0 = *(const float4*)(xrow);
      float4 a1 = *(const float4*)(xrow + 4);
      float xv[8] = {a0.x, a0.y, a0.z, a0.w, a1.x, a1.y, a1.z, a1.w};
      #pragma unroll
      for (int j = 0; j < 8; ++j) {
        u16 h = f2bf(xv[j]);
        ah[g].u[j] = h;
        al[g].u[j] = f2bf(xv[j] - bf2f(h));
      }
    }
    #pragma unroll
    for (int n = 0; n < 16; ++n) {
      size_t off = (size_t)(n * 16 + r) * 256 + ks * 32 + c * 8;
      bf16x8 whf = *(const bf16x8*)(Whw + off);
      bf16x8 wlf = *(const bf16x8*)(Wlw + off);
      #pragma unroll
      for (int g = 0; g < 2; ++g) {
        acc[g][n] = __builtin_amdgcn_mfma_f32_16x16x32_bf16(ah[g].b, whf, acc[g][n], 0, 0, 0);
        acc[g][n] = __builtin_amdgcn_mfma_f32_16x16x32_bf16(al[g].b, whf, acc[g][n], 0, 0, 0);
        acc[g][n] = __builtin_amdgcn_mfma_f32_16x16x32_bf16(ah[g].b, wlf, acc[g][n], 0, 0, 0);
      }
    }
  }

  if (w < 2) {
    f16* outp = (w == 0) ? Qf : Kf;
    #pragma unroll
    for (int g = 0; g < 2; ++g)
      #pragma unroll
      for (int n = 0; n < 16; ++n) {
        int col = n * 16 + r;
        float bb = bias[col];
        #pragma unroll
        for (int i = 0; i < 4; ++i) {
          float v = fmaxf(acc[g][n][i] + bb, 0.0f);
          outp[(size_t)(row0 + g * 16 + c * 4 + i) * 256 + col] = (f16)v;
        }
      }
  } else {
    #pragma unroll
    for (int g = 0; g < 2; ++g) {
      int grow = row0 + g * 16 + c * 4;
      int b = grow >> 12, s0 = grow & 4095;
      #pragma unroll
      for (int n = 0; n < 16; ++n) {
        int d = n * 16 + r;
        float bb = bias[d];
        f16x4 pk;
        #pragma unroll
        for (int i = 0; i < 4; ++i) pk[i] = (f16)(acc[g][n][i] + bb);
        *(f16x4*)(Vt + (size_t)(b * 256 + d) * 4096 + s0) = pk;
      }
    }
  }
}

// ---- Kernel C: flash attention, f16, split-K(4), 2-phase LDS double-buffer ----
// 512 blocks x 256 thr. Block: 128 q-rows (4 waves x 2 groups of 16), 1024 keys.
// Per 32-key tile: K[32][256] (16KB) + V^T[256][32] (16KB) staged via
// global_load_lds (linear LDS dest, XOR-swizzled GLOBAL src; reads same XOR).
__global__ __launch_bounds__(256, 2) void attn_kernel(
    const f16* __restrict__ Qf, const f16* __restrict__ Kf,
    const f16* __restrict__ Vt, f16* __restrict__ Opart, float* __restrict__ Ml) {
  __shared__ __align__(16) char Ks[2][16384];
  __shared__ __align__(16) char Vs[2][16384];
  __shared__ __align__(16) u16 Psm[4][2][16][40];   // 80B rows (16B-aligned)

  int bid = blockIdx.x;
  int xcd = bid & 7;                     // physical XCD = bid % 8
  int batch = xcd >> 1;                  // pin batch to XCD pair
  int kq = ((xcd & 1) << 1) | ((bid >> 3) & 1);
  int qtl = bid >> 4;                    // 0..31 q-tile within batch
  int tid = threadIdx.x, lane = tid & 63, wv = tid >> 6;
  int r = lane & 15, c = lane >> 4;
  int qrow0 = qtl * 128 + wv * 32;       // within batch
  int kv0 = kq * 1024;

  // Q fragments (32 rows x 256 d per wave) in registers
  f16x8 qf[2][8];
  #pragma unroll
  for (int g = 0; g < 2; ++g) {
    const f16* qrow = Qf + (size_t)(batch * 4096 + qrow0 + g * 16 + r) * 256;
    #pragma unroll
    for (int ks = 0; ks < 8; ++ks) qf[g][ks] = *(const f16x8*)(qrow + ks * 32 + c * 8);
  }

  f32x4 O[2][16];
  #pragma unroll
  for (int g = 0; g < 2; ++g)
    #pragma unroll
    for (int n = 0; n < 16; ++n) O[g][n] = (f32x4)0.0f;
  float m_[2][4], l_[2][4];
  #pragma unroll
  for (int g = 0; g < 2; ++g)
    #pragma unroll
    for (int i = 0; i < 4; ++i) { m_[g][i] = -3.0e38f; l_[g][i] = 0.0f; }

  const f16* Kbase = Kf + (size_t)(batch * 4096 + kv0) * 256;
  const f16* Vbase = Vt + (size_t)batch * 256 * 4096 + kv0;

#define STAGE(T, BF)                                                           \
  {                                                                            \
    _Pragma("unroll")                                                          \
    for (int rr = 0; rr < 4; ++rr) {                                           \
      int slot = rr * 256 + tid;                                               \
      int krow = slot >> 5;                                                    \
      int dby = ((slot & 31) << 4) ^ ((krow & 7) << 4);                        \
      const char* gsrc = (const char*)(Kbase + (size_t)((T) * 32 + krow) * 256) + dby; \
      __builtin_amdgcn_global_load_lds(                                        \
          (const __attribute__((address_space(1))) void*)gsrc,                 \
          (__attribute__((address_space(3))) void*)(Ks[BF] + slot * 16), 16, 0, 0); \
    }                                                                          \
    _Pragma("unroll")                                                          \
    for (int rr = 0; rr < 4; ++rr) {                                           \
      int slot = rr * 256 + tid;                                               \
      int vrow = slot >> 2;                                                    \
      int dby = ((slot & 3) << 4) ^ ((vrow & 3) << 4);                         \
      const char* gsrc = (const char*)(Vbase + (size_t)vrow * 4096 + (T) * 32) + dby; \
      __builtin_amdgcn_global_load_lds(                                        \
          (const __attribute__((address_space(1))) void*)gsrc,                 \
          (__attribute__((address_space(3))) void*)(Vs[BF] + slot * 16), 16, 0, 0); \
    }                                                                          \
  }

  STAGE(0, 0);
  __syncthreads();

  for (int t = 0; t < 32; ++t) {
    int bf = t & 1;
    if (t + 1 < 32) STAGE(t + 1, bf ^ 1);   // prefetch next tile (latency hides under compute)

    // S = Q K^T : per group 2 n-tiles; each kf feeds both groups
    f32x4 sA[2][2];
    #pragma unroll
    for (int g = 0; g < 2; ++g) { sA[g][0] = (f32x4)0.0f; sA[g][1] = (f32x4)0.0f; }
    #pragma unroll
    for (int ks = 0; ks < 8; ++ks) {
      #pragma unroll
      for (int n = 0; n < 2; ++n) {
        int krow = n * 16 + r;
        int dby = (ks * 64 + c * 16) ^ ((krow & 7) << 4);
        f16x8 kf = *(const f16x8*)(Ks[bf] + krow * 512 + dby);
        sA[0][n] = __builtin_amdgcn_mfma_f32_16x16x32_f16(qf[0][ks], kf, sA[0][n], 0, 0, 0);
        sA[1][n] = __builtin_amdgcn_mfma_f32_16x16x32_f16(qf[1][ks], kf, sA[1][n], 0, 0, 0);
      }
    }

    // online softmax (rows = c*4+i per group; keys = n*16 + r)
    float tmax[2][4];
    #pragma unroll
    for (int g = 0; g < 2; ++g)
      #pragma unroll
      for (int i = 0; i < 4; ++i) tmax[g][i] = fmaxf(sA[g][0][i], sA[g][1][i]);
    #pragma unroll
    for (int d = 1; d < 16; d <<= 1)
      #pragma unroll
      for (int g = 0; g < 2; ++g)
        #pragma unroll
        for (int i = 0; i < 4; ++i) tmax[g][i] = fmaxf(tmax[g][i], __shfl_xor(tmax[g][i], d));
    bool up = false;
    #pragma unroll
    for (int g = 0; g < 2; ++g)
      #pragma unroll
      for (int i = 0; i < 4; ++i) up = up || (tmax[g][i] > m_[g][i]);
    if (__any(up)) {
      #pragma unroll
      for (int g = 0; g < 2; ++g)
        #pragma unroll
        for (int i = 0; i < 4; ++i) {
          float mn = fmaxf(m_[g][i], tmax[g][i]);
          float sc = __expf(m_[g][i] - mn);
          m_[g][i] = mn; l_[g][i] *= sc;
          #pragma unroll
          for (int n = 0; n < 16; ++n) O[g][n][i] *= sc;
        }
    }

    // P = exp(S-m) -> per-wave LDS, accumulate row sums
    #pragma unroll
    for (int g = 0; g < 2; ++g) {
      float psum[4] = {0.f, 0.f, 0.f, 0.f};
      #pragma unroll
      for (int n = 0; n < 2; ++n)
        #pragma unroll
        for (int i = 0; i < 4; ++i) {
          float p = __expf(sA[g][n][i] - m_[g][i]);
          psum[i] += p;
          f16 ph = (f16)p;
          Psm[wv][g][c * 4 + i][n * 16 + r] = *(u16*)&ph;
        }
      #pragma unroll
      for (int d = 1; d < 16; d <<= 1)
        #pragma unroll
        for (int i = 0; i < 4; ++i) psum[i] += __shfl_xor(psum[i], d);
      #pragma unroll
      for (int i = 0; i < 4; ++i) l_[g][i] += psum[i];
    }

    // O += P V (each vf feeds both groups)
    f16x8 pf[2];
    #pragma unroll
    for (int g = 0; g < 2; ++g) pf[g] = *(const f16x8*)(&Psm[wv][g][r][c * 8]);
    #pragma unroll
    for (int n = 0; n < 16; ++n) {
      int vrow = n * 16 + r;
      int dby = (c * 16) ^ ((vrow & 3) << 4);
      f16x8 vf = *(const f16x8*)(Vs[bf] + vrow * 64 + dby);
      O[0][n] = __builtin_amdgcn_mfma_f32_16x16x32_f16(pf[0], vf, O[0][n], 0, 0, 0);
      O[1][n] = __builtin_amdgcn_mfma_f32_16x16x32_f16(pf[1], vf, O[1][n], 0, 0, 0);
    }

    __syncthreads();   // drains prefetch vmcnt + guards buffer reuse
  }

  // partial output (unnormalized O, plus m,l) for split-K merge
  #pragma unroll
  for (int g = 0; g < 2; ++g)
    #pragma unroll
    for (int n = 0; n < 16; ++n)
      #pragma unroll
      for (int i = 0; i < 4; ++i) {
        int grow = batch * 4096 + qrow0 + g * 16 + c * 4 + i;
        Opart[((size_t)kq * 16384 + grow) * 256 + n * 16 + r] = (f16)(O[g][n][i]);
      }
  if (r == 0) {
    #pragma unroll
    for (int g = 0; g < 2; ++g)
      #pragma unroll
      for (int i = 0; i < 4; ++i) {
        int grow = batch * 4096 + qrow0 + g * 16 + c * 4 + i;
        Ml[((size_t)kq * 16384 + grow) * 2] = m_[g][i];
        Ml[((size_t)kq * 16384 + grow) * 2 + 1] = l_[g][i];
      }
  }
#undef STAGE
}

// ---- Kernel D: split-K merge ----
__global__ __launch_bounds__(256) void merge_kernel(
    const f16* __restrict__ Opart, const float* __restrict__ Ml,
    float* __restrict__ out) {
  int gid = blockIdx.x * 256 + threadIdx.x;   // 524288 threads
  int row = gid >> 5, d0 = (gid & 31) * 8;
  float m[4], l[4];
  #pragma unroll
  for (int p = 0; p < 4; ++p) {
    m[p] = Ml[((size_t)p * 16384 + row) * 2];
    l[p] = Ml[((size_t)p * 16384 + row) * 2 + 1];
  }
  float M = fmaxf(fmaxf(m[0], m[1]), fmaxf(m[2], m[3]));
  float w[4], L = 0.f;
  #pragma unroll
  for (int p = 0; p < 4; ++p) { w[p] = __expf(m[p] - M); L += w[p] * l[p]; }
  float o[8] = {0.f, 0.f, 0.f, 0.f, 0.f, 0.f, 0.f, 0.f};
  #pragma unroll
  for (int p = 0; p < 4; ++p) {
    f16x8 v = *(const f16x8*)(Opart + ((size_t)p * 16384 + row) * 256 + d0);
    #pragma unroll
    for (int j = 0; j < 8; ++j) o[j] += w[p] * (float)v[j];
  }
  float invL = 1.0f / L;
  float4 o0 = {o[0] * invL, o[1] * invL, o[2] * invL, o[3] * invL};
  float4 o1 = {o[4] * invL, o[5] * invL, o[6] * invL, o[7] * invL};
  *(float4*)(out + (size_t)row * 256 + d0) = o0;
  *(float4*)(out + (size_t)row * 256 + d0 + 4) = o1;
}

extern "C" void kernel_launch(void* const* d_in, const int* in_sizes, int n_in,
                              void* d_out, int out_size, void* d_ws, size_t ws_size,
                              hipStream_t stream) {
  const float* x  = (const float*)d_in[0];
  const float* Wq = (const float*)d_in[1];
  const float* bq = (const float*)d_in[2];
  const float* Wk = (const float*)d_in[3];
  const float* bk = (const float*)d_in[4];
  const float* Wv = (const float*)d_in[5];
  const float* bv = (const float*)d_in[6];
  float* out = (float*)d_out;

  // ws layout (u16/f16 elems): Wh[3*65536] Wl[3*65536] | Qf Kf (16384*256 each)
  //                            | Vt[4*256*4096] | Opart[4*16384*256] | Ml f32[4*16384*2]
  u16* Wh = (u16*)d_ws;
  u16* Wl = Wh + 3 * 65536;
  f16* Qf = (f16*)(Wl + 3 * 65536);
  f16* Kf = Qf + (size_t)16384 * 256;
  f16* Vt = Kf + (size_t)16384 * 256;
  f16* Opart = Vt + (size_t)4 * 256 * 4096;
  float* Ml = (float*)(Opart + (size_t)4 * 16384 * 256);

  wt_kernel<<<48, 256, 0, stream>>>(Wq, Wk, Wv, Wh, Wl);
  proj_kernel<<<dim3(128, 3), 256, 0, stream>>>(x, bq, bk, bv, Wh, Wl, Qf, Kf, Vt);
  attn_kernel<<<512, 256, 0, stream>>>(Qf, Kf, Vt, Opart, Ml);
  merge_kernel<<<2048, 256, 0, stream>>>(Opart, Ml, out);
}

// Round 4
// 206.890 us; speedup vs baseline: 2.0067x; 1.2326x over previous
//
#include <hip/hip_runtime.h>
#include <stdint.h>

typedef __bf16 bf16;
typedef bf16 bf16x8 __attribute__((ext_vector_type(8)));
typedef _Float16 f16;
typedef f16 f16x8 __attribute__((ext_vector_type(8)));
typedef f16 f16x4 __attribute__((ext_vector_type(4)));
typedef float f32x4 __attribute__((ext_vector_type(4)));
typedef float f32x16 __attribute__((ext_vector_type(16)));
typedef unsigned short u16;
typedef unsigned int u32;
typedef u32 u32x2 __attribute__((ext_vector_type(2)));
typedef u16 u16x8v __attribute__((ext_vector_type(8)));

__device__ __forceinline__ u16 f2bf(float f) {
  u32 u = __float_as_uint(f);
  u32 r = u + 0x7fffu + ((u >> 16) & 1u);
  return (u16)(r >> 16);
}
__device__ __forceinline__ float bf2f(u16 h) { return __uint_as_float(((u32)h) << 16); }

__device__ __forceinline__ u32 pkrtz(float a, float b) {
  auto r = __builtin_amdgcn_cvt_pkrtz(a, b);   // f16x2: a->[15:0], b->[31:16]
  u32 u; __builtin_memcpy(&u, &r, 4);
  return u;
}

union ABu { u16x8v u; bf16x8 b; };
union PAu { u32 w[4]; f16x8 v; };

// ---- Kernel A: Wh/Wl[w][out][in] = split-bf16 of W_w[in][out] ----
__global__ void wt_kernel(const float* __restrict__ Wq, const float* __restrict__ Wk,
                          const float* __restrict__ Wv, u16* __restrict__ Wh,
                          u16* __restrict__ Wl) {
  int w = blockIdx.x >> 4;
  int chunk = blockIdx.x & 15;
  const float* W = (w == 0) ? Wq : (w == 1) ? Wk : Wv;
  int t = threadIdx.x;
  int o = chunk * 16 + (t & 15);
  int i0 = (t >> 4) * 16;
  u16x8v h0, h1, l0, l1;
  #pragma unroll
  for (int ii = 0; ii < 8; ++ii) {
    float v0 = W[(size_t)(i0 + ii) * 256 + o];
    u16 h = f2bf(v0); h0[ii] = h; l0[ii] = f2bf(v0 - bf2f(h));
    float v1 = W[(size_t)(i0 + 8 + ii) * 256 + o];
    h = f2bf(v1); h1[ii] = h; l1[ii] = f2bf(v1 - bf2f(h));
  }
  size_t base = (size_t)w * 65536 + (size_t)o * 256 + i0;
  *(u16x8v*)(Wh + base) = h0; *(u16x8v*)(Wh + base + 8) = h1;
  *(u16x8v*)(Wl + base) = l0; *(u16x8v*)(Wl + base + 8) = l1;
}

// ---- Kernel B: QKV projection (fp32-exact 3-pass bf16), outputs f16 ----
__global__ __launch_bounds__(256, 2) void proj_kernel(
    const float* __restrict__ x, const float* __restrict__ bq,
    const float* __restrict__ bk, const float* __restrict__ bv,
    const u16* __restrict__ Wh, const u16* __restrict__ Wl,
    f16* __restrict__ Qf, f16* __restrict__ Kf, f16* __restrict__ Vt) {
  int m = blockIdx.x, w = blockIdx.y;
  int tid = threadIdx.x, lane = tid & 63, wv = tid >> 6;
  int r = lane & 15, c = lane >> 4;
  int row0 = m * 128 + wv * 32;
  const u16* Whw = Wh + (size_t)w * 65536;
  const u16* Wlw = Wl + (size_t)w * 65536;
  const float* bias = (w == 0) ? bq : (w == 1) ? bk : bv;

  f32x4 acc[2][16];
  #pragma unroll
  for (int g = 0; g < 2; ++g)
    #pragma unroll
    for (int n = 0; n < 16; ++n) acc[g][n] = (f32x4)0.0f;

  #pragma unroll
  for (int ks = 0; ks < 8; ++ks) {
    ABu ah[2], al[2];
    #pragma unroll
    for (int g = 0; g < 2; ++g) {
      const float* xrow = x + (size_t)(row0 + g * 16 + r) * 256 + ks * 32 + c * 8;
      float4 a0 = *(const float4*)(xrow);
      float4 a1 = *(const float4*)(xrow + 4);
      float xv[8] = {a0.x, a0.y, a0.z, a0.w, a1.x, a1.y, a1.z, a1.w};
      #pragma unroll
      for (int j = 0; j < 8; ++j) {
        u16 h = f2bf(xv[j]);
        ah[g].u[j] = h;
        al[g].u[j] = f2bf(xv[j] - bf2f(h));
      }
    }
    #pragma unroll
    for (int n = 0; n < 16; ++n) {
      size_t off = (size_t)(n * 16 + r) * 256 + ks * 32 + c * 8;
      bf16x8 whf = *(const bf16x8*)(Whw + off);
      bf16x8 wlf = *(const bf16x8*)(Wlw + off);
      #pragma unroll
      for (int g = 0; g < 2; ++g) {
        acc[g][n] = __builtin_amdgcn_mfma_f32_16x16x32_bf16(ah[g].b, whf, acc[g][n], 0, 0, 0);
        acc[g][n] = __builtin_amdgcn_mfma_f32_16x16x32_bf16(al[g].b, whf, acc[g][n], 0, 0, 0);
        acc[g][n] = __builtin_amdgcn_mfma_f32_16x16x32_bf16(ah[g].b, wlf, acc[g][n], 0, 0, 0);
      }
    }
  }

  if (w < 2) {
    f16* outp = (w == 0) ? Qf : Kf;
    #pragma unroll
    for (int g = 0; g < 2; ++g)
      #pragma unroll
      for (int n = 0; n < 16; ++n) {
        int col = n * 16 + r;
        float bb = bias[col];
        #pragma unroll
        for (int i = 0; i < 4; ++i) {
          float v = fmaxf(acc[g][n][i] + bb, 0.0f);
          outp[(size_t)(row0 + g * 16 + c * 4 + i) * 256 + col] = (f16)v;
        }
      }
  } else {
    #pragma unroll
    for (int g = 0; g < 2; ++g) {
      int grow = row0 + g * 16 + c * 4;
      int b = grow >> 12, s0 = grow & 4095;
      #pragma unroll
      for (int n = 0; n < 16; ++n) {
        int d = n * 16 + r;
        float bb = bias[d];
        f16x4 pk;
        #pragma unroll
        for (int i = 0; i < 4; ++i) pk[i] = (f16)(acc[g][n][i] + bb);
        *(f16x4*)(Vt + (size_t)(b * 256 + d) * 4096 + s0) = pk;
      }
    }
  }
}

// ---- Kernel C: flash attention, swapped-QK^T 32x32 MFMA, in-register softmax ----
// 512 blocks x 4 waves, 32 q-rows/wave, KVBLK=32, split-K(4), LDS double-buffer.
// K [32][256] + V^T [256][32] f16 tiles staged via global_load_lds
// (linear LDS dest, XOR-swizzled GLOBAL src; reads apply the same XOR).
// Lane mapping: ln=lane&31 = q-col (QK D-layout) / d-col (PV D-layout); hi=lane>>5.
__global__ __launch_bounds__(256, 2) void attn_kernel(
    const f16* __restrict__ Qf, const f16* __restrict__ Kf,
    const f16* __restrict__ Vt, f16* __restrict__ Opart, float* __restrict__ Ml) {
  __shared__ __align__(16) char Ksm[2][16384];
  __shared__ __align__(16) char Vsm[2][16384];

  int bid = blockIdx.x;
  int xcd = bid & 7;                    // pin (batch, kq-pair) per XCD for L2 reuse
  int batch = xcd >> 1;
  int kq = ((xcd & 1) << 1) | ((bid >> 3) & 1);
  int qtl = bid >> 4;                   // 0..31
  int tid = threadIdx.x, lane = tid & 63, wv = tid >> 6;
  int ln = lane & 31, hi = lane >> 5;
  int q0 = qtl * 128 + wv * 32;         // q-row base (within batch) for this wave
  int kv0 = kq * 1024;

  // Q B-fragments in registers: qf[ks] elem j = Q[q0+ln][ks*16 + hi*8 + j]
  f16x8 qf[16];
  {
    const f16* qp = Qf + ((size_t)(batch * 4096 + q0 + ln)) * 256 + hi * 8;
    #pragma unroll
    for (int ks = 0; ks < 16; ++ks) qf[ks] = *(const f16x8*)(qp + ks * 16);
  }

  f32x16 O[8];
  #pragma unroll
  for (int dt = 0; dt < 8; ++dt) O[dt] = (f32x16)0.0f;
  float m_ = -1.0e30f, l_ = 0.0f;

  const char* Kbase = (const char*)(Kf + ((size_t)(batch * 4096 + kv0)) * 256);
  const char* Vbase = (const char*)(Vt + (size_t)batch * 1048576 + kv0);

#define STAGE(T, BF)                                                           \
  {                                                                            \
    _Pragma("unroll")                                                          \
    for (int rr = 0; rr < 4; ++rr) {                                           \
      int slot = rr * 256 + tid;                                               \
      int krow = slot >> 5;                                                    \
      int dby = ((slot & 31) << 4) ^ ((krow & 7) << 4);                        \
      const char* g = Kbase + (size_t)((T) * 32 + krow) * 512 + dby;           \
      __builtin_amdgcn_global_load_lds(                                        \
          (const __attribute__((address_space(1))) void*)g,                    \
          (__attribute__((address_space(3))) void*)(Ksm[BF] + slot * 16), 16, 0, 0); \
    }                                                                          \
    _Pragma("unroll")                                                          \
    for (int rr = 0; rr < 4; ++rr) {                                           \
      int slot = rr * 256 + tid;                                               \
      int vrow = slot >> 2;                                                    \
      int dby = ((slot & 3) << 4) ^ ((vrow & 3) << 4);                         \
      const char* g = Vbase + (size_t)vrow * 8192 + (T) * 64 + dby;            \
      __builtin_amdgcn_global_load_lds(                                        \
          (const __attribute__((address_space(1))) void*)g,                    \
          (__attribute__((address_space(3))) void*)(Vsm[BF] + slot * 16), 16, 0, 0); \
    }                                                                          \
  }

  STAGE(0, 0);
  __syncthreads();

  int kswz = (ln & 7) << 4;
  int vswz = (ln & 3) << 4;
  int hi16 = hi * 16;

  for (int t = 0; t < 32; ++t) {
    int bf = t & 1;
    if (t + 1 < 32) STAGE(t + 1, bf ^ 1);

    const char* Kc = Ksm[bf];
    const char* Vc = Vsm[bf];

    // S^T = K Q^T: A-frag = K[key=ln][k], accum D: row=key(crow), col=q=ln
    f32x16 sA = (f32x16)0.0f;
    __builtin_amdgcn_s_setprio(1);
    #pragma unroll
    for (int ks = 0; ks < 16; ++ks) {
      f16x8 kf = *(const f16x8*)(Kc + ln * 512 + ((ks * 32 + hi16) ^ kswz));
      sA = __builtin_amdgcn_mfma_f32_32x32x16_f16(kf, qf[ks], sA, 0, 0, 0);
    }
    __builtin_amdgcn_s_setprio(0);

    // lane-local softmax for q = ln (keys split across hi halves)
    float pm = sA[0];
    #pragma unroll
    for (int j = 1; j < 16; ++j) pm = fmaxf(pm, sA[j]);
    pm = fmaxf(pm, __shfl_xor(pm, 32));
    if (!__all(pm <= m_ + 8.0f)) {       // defer-max (T13): rescale only on growth >8
      float mn = fmaxf(m_, pm);
      float sc = __expf(m_ - mn);
      m_ = mn;
      l_ *= sc;
      #pragma unroll
      for (int rg = 0; rg < 16; ++rg) {
        float srg = __shfl(sc, (rg & 3) + 8 * (rg >> 2) + 4 * hi);
        #pragma unroll
        for (int dt = 0; dt < 8; ++dt) O[dt][rg] *= srg;
      }
    }
    float p[16], ps = 0.0f;
    #pragma unroll
    for (int j = 0; j < 16; ++j) { p[j] = __expf(sA[j] - m_); ps += p[j]; }
    ps += __shfl_xor(ps, 32);
    l_ += ps;

    // P -> PV A-frags: cvt_pkrtz pairs + permlane32_swap (swaps A_hi <-> B_lo)
    PAu pa0, pa1;
    {
      u32x2 r1 = __builtin_amdgcn_permlane32_swap(pkrtz(p[0], p[1]), pkrtz(p[4], p[5]), false, false);
      u32x2 r2 = __builtin_amdgcn_permlane32_swap(pkrtz(p[2], p[3]), pkrtz(p[6], p[7]), false, false);
      pa0.w[0] = r1[0]; pa0.w[1] = r2[0]; pa0.w[2] = r1[1]; pa0.w[3] = r2[1];
      u32x2 r3 = __builtin_amdgcn_permlane32_swap(pkrtz(p[8], p[9]), pkrtz(p[12], p[13]), false, false);
      u32x2 r4 = __builtin_amdgcn_permlane32_swap(pkrtz(p[10], p[11]), pkrtz(p[14], p[15]), false, false);
      pa1.w[0] = r3[0]; pa1.w[1] = r4[0]; pa1.w[2] = r3[1]; pa1.w[3] = r4[1];
    }

    // O += P V : B-frag = V[key][d=dt*32+ln]
    __builtin_amdgcn_s_setprio(1);
    #pragma unroll
    for (int dt = 0; dt < 8; ++dt) {
      const char* vr = Vc + (dt * 32 + ln) * 64;
      f16x8 vf0 = *(const f16x8*)(vr + ((0 + hi16) ^ vswz));
      O[dt] = __builtin_amdgcn_mfma_f32_32x32x16_f16(pa0.v, vf0, O[dt], 0, 0, 0);
      f16x8 vf1 = *(const f16x8*)(vr + ((32 + hi16) ^ vswz));
      O[dt] = __builtin_amdgcn_mfma_f32_32x32x16_f16(pa1.v, vf1, O[dt], 0, 0, 0);
    }
    __builtin_amdgcn_s_setprio(0);

    __syncthreads();   // drains prefetch vmcnt + guards dbuf reuse
  }

  // epilogue: store NORMALIZED O (f16-safe), plus (m,l) per q-row
  float invl = 1.0f / l_;
  #pragma unroll
  for (int rg = 0; rg < 16; ++rg) {
    int qr = (rg & 3) + 8 * (rg >> 2) + 4 * hi;
    float iv = __shfl(invl, qr);
    size_t row = (size_t)kq * 16384 + batch * 4096 + q0 + qr;
    #pragma unroll
    for (int dt = 0; dt < 8; ++dt)
      Opart[row * 256 + dt * 32 + ln] = (f16)(O[dt][rg] * iv);
  }
  if (hi == 0) {
    size_t grow = (size_t)kq * 16384 + batch * 4096 + q0 + ln;
    Ml[grow * 2] = m_;
    Ml[grow * 2 + 1] = l_;
  }
#undef STAGE
}

// ---- Kernel D: split-K merge (Opart is normalized; weight = exp(m-M)*l) ----
__global__ __launch_bounds__(256) void merge_kernel(
    const f16* __restrict__ Opart, const float* __restrict__ Ml,
    float* __restrict__ out) {
  int gid = blockIdx.x * 256 + threadIdx.x;
  int row = gid >> 5, d0 = (gid & 31) * 8;
  float m[4], l[4];
  #pragma unroll
  for (int p = 0; p < 4; ++p) {
    m[p] = Ml[((size_t)p * 16384 + row) * 2];
    l[p] = Ml[((size_t)p * 16384 + row) * 2 + 1];
  }
  float M = fmaxf(fmaxf(m[0], m[1]), fmaxf(m[2], m[3]));
  float wl[4], L = 0.f;
  #pragma unroll
  for (int p = 0; p < 4; ++p) { wl[p] = __expf(m[p] - M) * l[p]; L += wl[p]; }
  float o[8] = {0.f, 0.f, 0.f, 0.f, 0.f, 0.f, 0.f, 0.f};
  #pragma unroll
  for (int p = 0; p < 4; ++p) {
    f16x8 v = *(const f16x8*)(Opart + ((size_t)p * 16384 + row) * 256 + d0);
    #pragma unroll
    for (int j = 0; j < 8; ++j) o[j] += wl[p] * (float)v[j];
  }
  float invL = 1.0f / L;
  float4 o0 = {o[0] * invL, o[1] * invL, o[2] * invL, o[3] * invL};
  float4 o1 = {o[4] * invL, o[5] * invL, o[6] * invL, o[7] * invL};
  *(float4*)(out + (size_t)row * 256 + d0) = o0;
  *(float4*)(out + (size_t)row * 256 + d0 + 4) = o1;
}

extern "C" void kernel_launch(void* const* d_in, const int* in_sizes, int n_in,
                              void* d_out, int out_size, void* d_ws, size_t ws_size,
                              hipStream_t stream) {
  const float* x  = (const float*)d_in[0];
  const float* Wq = (const float*)d_in[1];
  const float* bq = (const float*)d_in[2];
  const float* Wk = (const float*)d_in[3];
  const float* bk = (const float*)d_in[4];
  const float* Wv = (const float*)d_in[5];
  const float* bv = (const float*)d_in[6];
  float* out = (float*)d_out;

  u16* Wh = (u16*)d_ws;
  u16* Wl = Wh + 3 * 65536;
  f16* Qf = (f16*)(Wl + 3 * 65536);
  f16* Kf = Qf + (size_t)16384 * 256;
  f16* Vt = Kf + (size_t)16384 * 256;
  f16* Opart = Vt + (size_t)4 * 256 * 4096;
  float* Ml = (float*)(Opart + (size_t)4 * 16384 * 256);

  wt_kernel<<<48, 256, 0, stream>>>(Wq, Wk, Wv, Wh, Wl);
  proj_kernel<<<dim3(128, 3), 256, 0, stream>>>(x, bq, bk, bv, Wh, Wl, Qf, Kf, Vt);
  attn_kernel<<<512, 256, 0, stream>>>(Qf, Kf, Vt, Opart, Ml);
  merge_kernel<<<2048, 256, 0, stream>>>(Opart, Ml, out);
}

// Round 5
// 168.181 us; speedup vs baseline: 2.4686x; 1.2302x over previous
//
#include <hip/hip_runtime.h>
#include <stdint.h>

typedef __bf16 bf16;
typedef bf16 bf16x8 __attribute__((ext_vector_type(8)));
typedef _Float16 f16;
typedef f16 f16x8 __attribute__((ext_vector_type(8)));
typedef f16 f16x4 __attribute__((ext_vector_type(4)));
typedef float f32x4 __attribute__((ext_vector_type(4)));
typedef float f32x16 __attribute__((ext_vector_type(16)));
typedef unsigned short u16;
typedef unsigned int u32;
typedef u32 u32x2 __attribute__((ext_vector_type(2)));
typedef u16 u16x8v __attribute__((ext_vector_type(8)));

__device__ __forceinline__ u16 f2bf(float f) {
  u32 u = __float_as_uint(f);
  u32 r = u + 0x7fffu + ((u >> 16) & 1u);
  return (u16)(r >> 16);
}
__device__ __forceinline__ float bf2f(u16 h) { return __uint_as_float(((u32)h) << 16); }

__device__ __forceinline__ u32 pkrtz(float a, float b) {
  auto r = __builtin_amdgcn_cvt_pkrtz(a, b);   // f16x2: a->[15:0], b->[31:16]
  u32 u; __builtin_memcpy(&u, &r, 4);
  return u;
}

union ABu { u16x8v u; bf16x8 b; };
union PAu { u32 w[4]; f16x8 v; };

// ---- Kernel A: Wh/Wl[w][out][in] = split-bf16 of W_w[in][out] ----
__global__ void wt_kernel(const float* __restrict__ Wq, const float* __restrict__ Wk,
                          const float* __restrict__ Wv, u16* __restrict__ Wh,
                          u16* __restrict__ Wl) {
  int w = blockIdx.x >> 4;
  int chunk = blockIdx.x & 15;
  const float* W = (w == 0) ? Wq : (w == 1) ? Wk : Wv;
  int t = threadIdx.x;
  int o = chunk * 16 + (t & 15);
  int i0 = (t >> 4) * 16;
  u16x8v h0, h1, l0, l1;
  #pragma unroll
  for (int ii = 0; ii < 8; ++ii) {
    float v0 = W[(size_t)(i0 + ii) * 256 + o];
    u16 h = f2bf(v0); h0[ii] = h; l0[ii] = f2bf(v0 - bf2f(h));
    float v1 = W[(size_t)(i0 + 8 + ii) * 256 + o];
    h = f2bf(v1); h1[ii] = h; l1[ii] = f2bf(v1 - bf2f(h));
  }
  size_t base = (size_t)w * 65536 + (size_t)o * 256 + i0;
  *(u16x8v*)(Wh + base) = h0; *(u16x8v*)(Wh + base + 8) = h1;
  *(u16x8v*)(Wl + base) = l0; *(u16x8v*)(Wl + base + 8) = l1;
}

// ---- Kernel B: QKV projection (fp32-exact 3-pass bf16), W slices staged in LDS ----
// grid (128, 3): 128-row tiles, 4 waves x 32 rows (2 groups of 16).
__global__ __launch_bounds__(256, 2) void proj_kernel(
    const float* __restrict__ x, const float* __restrict__ bq,
    const float* __restrict__ bk, const float* __restrict__ bv,
    const u16* __restrict__ Wh, const u16* __restrict__ Wl,
    f16* __restrict__ Qf, f16* __restrict__ Kf, f16* __restrict__ Vt) {
  __shared__ __align__(16) char Whs[16384];   // [256 out-rows][32 in] bf16, swizzled
  __shared__ __align__(16) char Wls[16384];

  int m = blockIdx.x, w = blockIdx.y;
  int tid = threadIdx.x, lane = tid & 63, wv = tid >> 6;
  int r = lane & 15, c = lane >> 4;
  int row0 = m * 128 + wv * 32;
  const char* Whw = (const char*)(Wh + (size_t)w * 65536);
  const char* Wlw = (const char*)(Wl + (size_t)w * 65536);
  const float* bias = (w == 0) ? bq : (w == 1) ? bk : bv;

  f32x4 acc[2][16];
  #pragma unroll
  for (int g = 0; g < 2; ++g)
    #pragma unroll
    for (int n = 0; n < 16; ++n) acc[g][n] = (f32x4)0.0f;

  for (int ks = 0; ks < 8; ++ks) {
    if (ks) __syncthreads();                     // prior slice reads done
    // stage Wh/Wl slice [256][32] (16KB each) via DMA, V-style swizzle
    #pragma unroll
    for (int ss = 0; ss < 4; ++ss) {
      int slot = ss * 256 + tid;
      int row = slot >> 2, c4 = slot & 3;
      int dby = (c4 << 4) ^ (((row >> 1) & 3) << 4);
      const char* gh = Whw + (size_t)row * 512 + ks * 64 + dby;
      const char* gl = Wlw + (size_t)row * 512 + ks * 64 + dby;
      __builtin_amdgcn_global_load_lds(
          (const __attribute__((address_space(1))) void*)gh,
          (__attribute__((address_space(3))) void*)(Whs + slot * 16), 16, 0, 0);
      __builtin_amdgcn_global_load_lds(
          (const __attribute__((address_space(1))) void*)gl,
          (__attribute__((address_space(3))) void*)(Wls + slot * 16), 16, 0, 0);
    }
    __syncthreads();                             // drains DMA (vmcnt 0)

    ABu ah[2], al[2];
    #pragma unroll
    for (int g = 0; g < 2; ++g) {
      const float* xrow = x + (size_t)(row0 + g * 16 + r) * 256 + ks * 32 + c * 8;
      float4 a0 = *(const float4*)(xrow);
      float4 a1 = *(const float4*)(xrow + 4);
      float xv[8] = {a0.x, a0.y, a0.z, a0.w, a1.x, a1.y, a1.z, a1.w};
      #pragma unroll
      for (int j = 0; j < 8; ++j) {
        u16 h = f2bf(xv[j]);
        ah[g].u[j] = h;
        al[g].u[j] = f2bf(xv[j] - bf2f(h));
      }
    }
    #pragma unroll
    for (int n = 0; n < 16; ++n) {
      int wrow = n * 16 + r;
      int wof = (c * 16) ^ (((wrow >> 1) & 3) << 4);
      bf16x8 whf = *(const bf16x8*)(Whs + wrow * 64 + wof);
      bf16x8 wlf = *(const bf16x8*)(Wls + wrow * 64 + wof);
      #pragma unroll
      for (int g = 0; g < 2; ++g) {
        acc[g][n] = __builtin_amdgcn_mfma_f32_16x16x32_bf16(ah[g].b, whf, acc[g][n], 0, 0, 0);
        acc[g][n] = __builtin_amdgcn_mfma_f32_16x16x32_bf16(al[g].b, whf, acc[g][n], 0, 0, 0);
        acc[g][n] = __builtin_amdgcn_mfma_f32_16x16x32_bf16(ah[g].b, wlf, acc[g][n], 0, 0, 0);
      }
    }
  }

  if (w < 2) {
    f16* outp = (w == 0) ? Qf : Kf;
    #pragma unroll
    for (int g = 0; g < 2; ++g)
      #pragma unroll
      for (int n = 0; n < 16; ++n) {
        int col = n * 16 + r;
        float bb = bias[col];
        #pragma unroll
        for (int i = 0; i < 4; ++i) {
          float v = fmaxf(acc[g][n][i] + bb, 0.0f);
          outp[(size_t)(row0 + g * 16 + c * 4 + i) * 256 + col] = (f16)v;
        }
      }
  } else {
    #pragma unroll
    for (int g = 0; g < 2; ++g) {
      int grow = row0 + g * 16 + c * 4;
      int b = grow >> 12, s0 = grow & 4095;
      #pragma unroll
      for (int n = 0; n < 16; ++n) {
        int d = n * 16 + r;
        float bb = bias[d];
        f16x4 pk;
        #pragma unroll
        for (int i = 0; i < 4; ++i) pk[i] = (f16)(acc[g][n][i] + bb);
        *(f16x4*)(Vt + (size_t)(b * 256 + d) * 4096 + s0) = pk;
      }
    }
  }
}

// ---- Kernel C: flash attention, swapped-QK^T 32x32, PV(t-1) || QK(t) pipeline ----
// 512 blocks x 4 waves, 32 q-rows/wave, KVBLK=32, split-K(4).
// K double-buffered (2x16KB), V triple-buffered (3x16KB) = 80KB -> 2 blocks/CU.
// Counted vmcnt(8) + raw s_barrier (no full drain in main loop).
__global__ __launch_bounds__(256, 2) void attn_kernel(
    const f16* __restrict__ Qf, const f16* __restrict__ Kf,
    const f16* __restrict__ Vt, f16* __restrict__ Opart, float* __restrict__ Ml) {
  __shared__ __align__(16) char Ksm[2][16384];
  __shared__ __align__(16) char Vsm[3][16384];

  int bid = blockIdx.x;
  int xcd = bid & 7;                    // pin (batch, kq-pair) per XCD for L2 reuse
  int batch = xcd >> 1;
  int kq = ((xcd & 1) << 1) | ((bid >> 3) & 1);
  int qtl = bid >> 4;                   // 0..31
  int tid = threadIdx.x, lane = tid & 63, wv = tid >> 6;
  int ln = lane & 31, hi = lane >> 5;
  int q0 = qtl * 128 + wv * 32;
  int kv0 = kq * 1024;

  // Q B-fragments: qf[ks] elem j = Q[q0+ln][ks*16 + hi*8 + j]
  f16x8 qf[16];
  {
    const f16* qp = Qf + ((size_t)(batch * 4096 + q0 + ln)) * 256 + hi * 8;
    #pragma unroll
    for (int ks = 0; ks < 16; ++ks) qf[ks] = *(const f16x8*)(qp + ks * 16);
  }

  f32x16 O[8];
  #pragma unroll
  for (int dt = 0; dt < 8; ++dt) O[dt] = (f32x16)0.0f;
  float m_ = -1.0e30f, l_ = 0.0f;
  PAu pa0_, pa1_;

  const char* Kbase = (const char*)(Kf + ((size_t)(batch * 4096 + kv0)) * 256);
  const char* Vbase = (const char*)(Vt + (size_t)batch * 1048576 + kv0);

  // K swizzle: slot-chunk XOR (row&7). V swizzle: XOR (row>>1)&3 — period 4 vs
  // 64B-row bank-period 2 => 8-lane groups land on 8 distinct bank quads.
#define STAGE(T, KB, VB)                                                       \
  {                                                                            \
    _Pragma("unroll")                                                          \
    for (int rr = 0; rr < 4; ++rr) {                                           \
      int slot = rr * 256 + tid;                                               \
      int krow = slot >> 5;                                                    \
      int dby = ((slot & 31) << 4) ^ ((krow & 7) << 4);                        \
      const char* g = Kbase + (size_t)((T) * 32 + krow) * 512 + dby;           \
      __builtin_amdgcn_global_load_lds(                                        \
          (const __attribute__((address_space(1))) void*)g,                    \
          (__attribute__((address_space(3))) void*)(Ksm[KB] + slot * 16), 16, 0, 0); \
    }                                                                          \
    _Pragma("unroll")                                                          \
    for (int rr = 0; rr < 4; ++rr) {                                           \
      int slot = rr * 256 + tid;                                               \
      int vrow = slot >> 2;                                                    \
      int dby = ((slot & 3) << 4) ^ (((vrow >> 1) & 3) << 4);                  \
      const char* g = Vbase + (size_t)vrow * 8192 + (T) * 64 + dby;            \
      __builtin_amdgcn_global_load_lds(                                        \
          (const __attribute__((address_space(1))) void*)g,                    \
          (__attribute__((address_space(3))) void*)(Vsm[VB] + slot * 16), 16, 0, 0); \
    }                                                                          \
  }

  int kswz = (ln & 7) << 4;
  int vswz = ((ln >> 1) & 3) << 4;
  int hi16 = hi * 16;

  // QK(T) [+ PV(T-1) interleaved] + softmax(T) -> pa0_/pa1_, m_, l_
#define QKPV(T, DOPV)                                                          \
  {                                                                            \
    const char* Kc = Ksm[(T) & 1];                                             \
    const char* Vc = Vsm[((T) + 2) % 3];                                       \
    f32x16 sA = (f32x16)0.0f;                                                  \
    __builtin_amdgcn_s_setprio(1);                                             \
    _Pragma("unroll")                                                          \
    for (int ks = 0; ks < 16; ++ks) {                                          \
      f16x8 kf = *(const f16x8*)(Kc + ln * 512 + ((ks * 32 + hi16) ^ kswz));   \
      sA = __builtin_amdgcn_mfma_f32_32x32x16_f16(kf, qf[ks], sA, 0, 0, 0);    \
      if (DOPV) {                                                              \
        int dt = ks >> 1, half = ks & 1;                                       \
        f16x8 vf = *(const f16x8*)(Vc + (dt * 32 + ln) * 64 +                  \
                                   ((half * 32 + hi16) ^ vswz));               \
        O[dt] = __builtin_amdgcn_mfma_f32_32x32x16_f16(                        \
            half ? pa1_.v : pa0_.v, vf, O[dt], 0, 0, 0);                       \
      }                                                                        \
    }                                                                          \
    __builtin_amdgcn_s_setprio(0);                                             \
    float pm = fmaxf(                                                          \
        fmaxf(fmaxf(fmaxf(sA[0], sA[1]), fmaxf(sA[2], sA[3])),                 \
              fmaxf(fmaxf(sA[4], sA[5]), fmaxf(sA[6], sA[7]))),                \
        fmaxf(fmaxf(fmaxf(sA[8], sA[9]), fmaxf(sA[10], sA[11])),               \
              fmaxf(fmaxf(sA[12], sA[13]), fmaxf(sA[14], sA[15]))));           \
    pm = fmaxf(pm, __shfl_xor(pm, 32));                                        \
    if (!__all(pm <= m_ + 8.0f)) {                                             \
      float mn = fmaxf(m_, pm);                                                \
      float sc = __expf(m_ - mn);                                              \
      m_ = mn; l_ *= sc;                                                       \
      _Pragma("unroll")                                                        \
      for (int rg = 0; rg < 16; ++rg) {                                        \
        float srg = __shfl(sc, (rg & 3) + 8 * (rg >> 2) + 4 * hi);             \
        _Pragma("unroll")                                                      \
        for (int dt = 0; dt < 8; ++dt) O[dt][rg] *= srg;                       \
      }                                                                        \
    }                                                                          \
    float p_[16];                                                              \
    _Pragma("unroll")                                                          \
    for (int j = 0; j < 16; ++j) p_[j] = __expf(sA[j] - m_);                   \
    float ps = (((p_[0] + p_[1]) + (p_[2] + p_[3])) +                          \
                ((p_[4] + p_[5]) + (p_[6] + p_[7]))) +                         \
               (((p_[8] + p_[9]) + (p_[10] + p_[11])) +                        \
                ((p_[12] + p_[13]) + (p_[14] + p_[15])));                      \
    ps += __shfl_xor(ps, 32);                                                  \
    l_ += ps;                                                                  \
    {                                                                          \
      u32x2 r1 = __builtin_amdgcn_permlane32_swap(pkrtz(p_[0], p_[1]), pkrtz(p_[4], p_[5]), false, false); \
      u32x2 r2 = __builtin_amdgcn_permlane32_swap(pkrtz(p_[2], p_[3]), pkrtz(p_[6], p_[7]), false, false); \
      pa0_.w[0] = r1[0]; pa0_.w[1] = r2[0]; pa0_.w[2] = r1[1]; pa0_.w[3] = r2[1]; \
      u32x2 r3 = __builtin_amdgcn_permlane32_swap(pkrtz(p_[8], p_[9]), pkrtz(p_[12], p_[13]), false, false); \
      u32x2 r4 = __builtin_amdgcn_permlane32_swap(pkrtz(p_[10], p_[11]), pkrtz(p_[14], p_[15]), false, false); \
      pa1_.w[0] = r3[0]; pa1_.w[1] = r4[0]; pa1_.w[2] = r3[1]; pa1_.w[3] = r4[1]; \
    }                                                                          \
  }

  STAGE(0, 0, 0);
  STAGE(1, 1, 1);
  asm volatile("s_waitcnt vmcnt(8)" ::: "memory");   // stage(0) landed
  __builtin_amdgcn_sched_barrier(0);
  __builtin_amdgcn_s_barrier();
  QKPV(0, false);                                     // peel: no PV yet

  for (int t = 1; t < 32; ++t) {
    __builtin_amdgcn_s_barrier();                     // all reads of reused bufs done
    if (t < 31) {
      int kb = (t + 1) & 1, vb = (t + 1) % 3;
      STAGE(t + 1, kb, vb);
      asm volatile("s_waitcnt vmcnt(8)" ::: "memory");  // stage(t) landed
    } else {
      asm volatile("s_waitcnt vmcnt(0)" ::: "memory");
    }
    __builtin_amdgcn_sched_barrier(0);
    __builtin_amdgcn_s_barrier();                     // stage(t) visible to all
    QKPV(t, true);                                    // QK(t) || PV(t-1)
  }

  // tail: PV(31) from Vsm[31 % 3]
  {
    const char* Vc = Vsm[31 % 3];
    #pragma unroll
    for (int ks = 0; ks < 16; ++ks) {
      int dt = ks >> 1, half = ks & 1;
      f16x8 vf = *(const f16x8*)(Vc + (dt * 32 + ln) * 64 + ((half * 32 + hi16) ^ vswz));
      O[dt] = __builtin_amdgcn_mfma_f32_32x32x16_f16(half ? pa1_.v : pa0_.v, vf, O[dt], 0, 0, 0);
    }
  }

  // epilogue: store NORMALIZED O (f16-safe), plus (m,l) per q-row
  float invl = 1.0f / l_;
  #pragma unroll
  for (int rg = 0; rg < 16; ++rg) {
    int qr = (rg & 3) + 8 * (rg >> 2) + 4 * hi;
    float iv = __shfl(invl, qr);
    size_t row = (size_t)kq * 16384 + batch * 4096 + q0 + qr;
    #pragma unroll
    for (int dt = 0; dt < 8; ++dt)
      Opart[row * 256 + dt * 32 + ln] = (f16)(O[dt][rg] * iv);
  }
  if (hi == 0) {
    size_t grow = (size_t)kq * 16384 + batch * 4096 + q0 + ln;
    Ml[grow * 2] = m_;
    Ml[grow * 2 + 1] = l_;
  }
#undef STAGE
#undef QKPV
}

// ---- Kernel D: split-K merge (Opart normalized; weight = exp(m-M)*l) ----
__global__ __launch_bounds__(256) void merge_kernel(
    const f16* __restrict__ Opart, const float* __restrict__ Ml,
    float* __restrict__ out) {
  int gid = blockIdx.x * 256 + threadIdx.x;
  int row = gid >> 5, d0 = (gid & 31) * 8;
  float m[4], l[4];
  #pragma unroll
  for (int p = 0; p < 4; ++p) {
    m[p] = Ml[((size_t)p * 16384 + row) * 2];
    l[p] = Ml[((size_t)p * 16384 + row) * 2 + 1];
  }
  float M = fmaxf(fmaxf(m[0], m[1]), fmaxf(m[2], m[3]));
  float wl[4], L = 0.f;
  #pragma unroll
  for (int p = 0; p < 4; ++p) { wl[p] = __expf(m[p] - M) * l[p]; L += wl[p]; }
  float o[8] = {0.f, 0.f, 0.f, 0.f, 0.f, 0.f, 0.f, 0.f};
  #pragma unroll
  for (int p = 0; p < 4; ++p) {
    f16x8 v = *(const f16x8*)(Opart + ((size_t)p * 16384 + row) * 256 + d0);
    #pragma unroll
    for (int j = 0; j < 8; ++j) o[j] += wl[p] * (float)v[j];
  }
  float invL = 1.0f / L;
  float4 o0 = {o[0] * invL, o[1] * invL, o[2] * invL, o[3] * invL};
  float4 o1 = {o[4] * invL, o[5] * invL, o[6] * invL, o[7] * invL};
  *(float4*)(out + (size_t)row * 256 + d0) = o0;
  *(float4*)(out + (size_t)row * 256 + d0 + 4) = o1;
}

extern "C" void kernel_launch(void* const* d_in, const int* in_sizes, int n_in,
                              void* d_out, int out_size, void* d_ws, size_t ws_size,
                              hipStream_t stream) {
  const float* x  = (const float*)d_in[0];
  const float* Wq = (const float*)d_in[1];
  const float* bq = (const float*)d_in[2];
  const float* Wk = (const float*)d_in[3];
  const float* bk = (const float*)d_in[4];
  const float* Wv = (const float*)d_in[5];
  const float* bv = (const float*)d_in[6];
  float* out = (float*)d_out;

  u16* Wh = (u16*)d_ws;
  u16* Wl = Wh + 3 * 65536;
  f16* Qf = (f16*)(Wl + 3 * 65536);
  f16* Kf = Qf + (size_t)16384 * 256;
  f16* Vt = Kf + (size_t)16384 * 256;
  f16* Opart = Vt + (size_t)4 * 256 * 4096;
  float* Ml = (float*)(Opart + (size_t)4 * 16384 * 256);

  wt_kernel<<<48, 256, 0, stream>>>(Wq, Wk, Wv, Wh, Wl);
  proj_kernel<<<dim3(128, 3), 256, 0, stream>>>(x, bq, bk, bv, Wh, Wl, Qf, Kf, Vt);
  attn_kernel<<<512, 256, 0, stream>>>(Qf, Kf, Vt, Opart, Ml);
  merge_kernel<<<2048, 256, 0, stream>>>(Opart, Ml, out);
}

// Round 6
// 157.386 us; speedup vs baseline: 2.6379x; 1.0686x over previous
//
#include <hip/hip_runtime.h>
#include <stdint.h>

typedef __bf16 bf16;
typedef bf16 bf16x8 __attribute__((ext_vector_type(8)));
typedef _Float16 f16;
typedef f16 f16x8 __attribute__((ext_vector_type(8)));
typedef f16 f16x4 __attribute__((ext_vector_type(4)));
typedef float f32x4 __attribute__((ext_vector_type(4)));
typedef float f32x16 __attribute__((ext_vector_type(16)));
typedef unsigned short u16;
typedef unsigned int u32;
typedef u32 u32x2 __attribute__((ext_vector_type(2)));
typedef u16 u16x8v __attribute__((ext_vector_type(8)));

__device__ __forceinline__ u16 f2bf(float f) {
  u32 u = __float_as_uint(f);
  u32 r = u + 0x7fffu + ((u >> 16) & 1u);
  return (u16)(r >> 16);
}
__device__ __forceinline__ float bf2f(u16 h) { return __uint_as_float(((u32)h) << 16); }

__device__ __forceinline__ u32 pkrtz(float a, float b) {
  auto r = __builtin_amdgcn_cvt_pkrtz(a, b);   // f16x2: a->[15:0], b->[31:16]
  u32 u; __builtin_memcpy(&u, &r, 4);
  return u;
}

union ABu { u16x8v u; bf16x8 b; };
union PAu { u32 w[4]; f16x8 v; };

// ---- Kernel A: Wh/Wl[w][out][in] = split-bf16 of W_w[in][out] ----
__global__ void wt_kernel(const float* __restrict__ Wq, const float* __restrict__ Wk,
                          const float* __restrict__ Wv, u16* __restrict__ Wh,
                          u16* __restrict__ Wl) {
  int w = blockIdx.x >> 4;
  int chunk = blockIdx.x & 15;
  const float* W = (w == 0) ? Wq : (w == 1) ? Wk : Wv;
  int t = threadIdx.x;
  int o = chunk * 16 + (t & 15);
  int i0 = (t >> 4) * 16;
  u16x8v h0, h1, l0, l1;
  #pragma unroll
  for (int ii = 0; ii < 8; ++ii) {
    float v0 = W[(size_t)(i0 + ii) * 256 + o];
    u16 h = f2bf(v0); h0[ii] = h; l0[ii] = f2bf(v0 - bf2f(h));
    float v1 = W[(size_t)(i0 + 8 + ii) * 256 + o];
    h = f2bf(v1); h1[ii] = h; l1[ii] = f2bf(v1 - bf2f(h));
  }
  size_t base = (size_t)w * 65536 + (size_t)o * 256 + i0;
  *(u16x8v*)(Wh + base) = h0; *(u16x8v*)(Wh + base + 8) = h1;
  *(u16x8v*)(Wl + base) = l0; *(u16x8v*)(Wl + base + 8) = l1;
}

// ---- Kernel B: QKV projection (fp32-exact 3-pass bf16), W slices staged in LDS ----
__global__ __launch_bounds__(256, 2) void proj_kernel(
    const float* __restrict__ x, const float* __restrict__ bq,
    const float* __restrict__ bk, const float* __restrict__ bv,
    const u16* __restrict__ Wh, const u16* __restrict__ Wl,
    f16* __restrict__ Qf, f16* __restrict__ Kf, f16* __restrict__ Vt) {
  __shared__ __align__(16) char Whs[16384];   // [256 out-rows][32 in] bf16, swizzled
  __shared__ __align__(16) char Wls[16384];

  int m = blockIdx.x, w = blockIdx.y;
  int tid = threadIdx.x, lane = tid & 63, wv = tid >> 6;
  int r = lane & 15, c = lane >> 4;
  int row0 = m * 128 + wv * 32;
  const char* Whw = (const char*)(Wh + (size_t)w * 65536);
  const char* Wlw = (const char*)(Wl + (size_t)w * 65536);
  const float* bias = (w == 0) ? bq : (w == 1) ? bk : bv;

  f32x4 acc[2][16];
  #pragma unroll
  for (int g = 0; g < 2; ++g)
    #pragma unroll
    for (int n = 0; n < 16; ++n) acc[g][n] = (f32x4)0.0f;

  for (int ks = 0; ks < 8; ++ks) {
    if (ks) __syncthreads();
    #pragma unroll
    for (int ss = 0; ss < 4; ++ss) {
      int slot = ss * 256 + tid;
      int row = slot >> 2, c4 = slot & 3;
      int dby = (c4 << 4) ^ (((row >> 1) & 3) << 4);
      const char* gh = Whw + (size_t)row * 512 + ks * 64 + dby;
      const char* gl = Wlw + (size_t)row * 512 + ks * 64 + dby;
      __builtin_amdgcn_global_load_lds(
          (const __attribute__((address_space(1))) void*)gh,
          (__attribute__((address_space(3))) void*)(Whs + slot * 16), 16, 0, 0);
      __builtin_amdgcn_global_load_lds(
          (const __attribute__((address_space(1))) void*)gl,
          (__attribute__((address_space(3))) void*)(Wls + slot * 16), 16, 0, 0);
    }
    __syncthreads();

    ABu ah[2], al[2];
    #pragma unroll
    for (int g = 0; g < 2; ++g) {
      const float* xrow = x + (size_t)(row0 + g * 16 + r) * 256 + ks * 32 + c * 8;
      float4 a0 = *(const float4*)(xrow);
      float4 a1 = *(const float4*)(xrow + 4);
      float xv[8] = {a0.x, a0.y, a0.z, a0.w, a1.x, a1.y, a1.z, a1.w};
      #pragma unroll
      for (int j = 0; j < 8; ++j) {
        u16 h = f2bf(xv[j]);
        ah[g].u[j] = h;
        al[g].u[j] = f2bf(xv[j] - bf2f(h));
      }
    }
    #pragma unroll
    for (int n = 0; n < 16; ++n) {
      int wrow = n * 16 + r;
      int wof = (c * 16) ^ (((wrow >> 1) & 3) << 4);
      bf16x8 whf = *(const bf16x8*)(Whs + wrow * 64 + wof);
      bf16x8 wlf = *(const bf16x8*)(Wls + wrow * 64 + wof);
      #pragma unroll
      for (int g = 0; g < 2; ++g) {
        acc[g][n] = __builtin_amdgcn_mfma_f32_16x16x32_bf16(ah[g].b, whf, acc[g][n], 0, 0, 0);
        acc[g][n] = __builtin_amdgcn_mfma_f32_16x16x32_bf16(al[g].b, whf, acc[g][n], 0, 0, 0);
        acc[g][n] = __builtin_amdgcn_mfma_f32_16x16x32_bf16(ah[g].b, wlf, acc[g][n], 0, 0, 0);
      }
    }
  }

  if (w < 2) {
    f16* outp = (w == 0) ? Qf : Kf;
    #pragma unroll
    for (int g = 0; g < 2; ++g)
      #pragma unroll
      for (int n = 0; n < 16; ++n) {
        int col = n * 16 + r;
        float bb = bias[col];
        #pragma unroll
        for (int i = 0; i < 4; ++i) {
          float v = fmaxf(acc[g][n][i] + bb, 0.0f);
          outp[(size_t)(row0 + g * 16 + c * 4 + i) * 256 + col] = (f16)v;
        }
      }
  } else {
    #pragma unroll
    for (int g = 0; g < 2; ++g) {
      int grow = row0 + g * 16 + c * 4;
      int b = grow >> 12, s0 = grow & 4095;
      #pragma unroll
      for (int n = 0; n < 16; ++n) {
        int d = n * 16 + r;
        float bb = bias[d];
        f16x4 pk;
        #pragma unroll
        for (int i = 0; i < 4; ++i) pk[i] = (f16)(acc[g][n][i] + bb);
        *(f16x4*)(Vt + (size_t)(b * 256 + d) * 4096 + s0) = pk;
      }
    }
  }
}

// ---- Kernel C: flash attention ----
// 256 blocks x 8 waves (512 thr), 32 q-rows/wave (256/block), KVBLK=64, splitK=4.
// K dbuf 2x32KB + V dbuf 2x32KB = 128KB LDS -> 1 block/CU, 2 waves/SIMD.
// Per round: stage(t+1), vmcnt(8), then QK(h0) -> sm -> QK(h1)||PV(h0) -> sm -> PV(h1).
__global__ __launch_bounds__(512, 2) void attn_kernel(
    const f16* __restrict__ Qf, const f16* __restrict__ Kf,
    const f16* __restrict__ Vt, f16* __restrict__ Opart, float* __restrict__ Ml) {
  __shared__ __align__(16) char Ksm[2][32768];   // [64 keys][256 d] f16, swizzled
  __shared__ __align__(16) char Vsm[2][32768];   // [256 d][64 keys] f16, swizzled

  int bid = blockIdx.x;                 // 256 blocks
  int xcd = bid & 7;                    // pin (batch, kq-pair) per XCD for L2 reuse
  int batch = xcd >> 1;
  int kq = ((xcd & 1) << 1) | ((bid >> 3) & 1);
  int qtl = bid >> 4;                   // 0..15
  int tid = threadIdx.x, lane = tid & 63, wv = tid >> 6;   // wv 0..7
  int ln = lane & 31, hi = lane >> 5;
  int q0 = qtl * 256 + wv * 32;
  int kv0 = kq * 1024;

  // Q B-fragments: qf[ks] elem j = Q[q0+ln][ks*16 + hi*8 + j]
  f16x8 qf[16];
  {
    const f16* qp = Qf + ((size_t)(batch * 4096 + q0 + ln)) * 256 + hi * 8;
    #pragma unroll
    for (int ks = 0; ks < 16; ++ks) qf[ks] = *(const f16x8*)(qp + ks * 16);
  }

  f32x16 O[8];
  #pragma unroll
  for (int dt = 0; dt < 8; ++dt) O[dt] = (f32x16)0.0f;
  float m_ = -1.0e30f, l_ = 0.0f;

  const char* Kbase = (const char*)(Kf + ((size_t)(batch * 4096 + kv0)) * 256);
  const char* Vbase = (const char*)(Vt + (size_t)batch * 1048576 + kv0);

  // K rows 512B (bank-period 0 mod 128B) -> XOR (row&7)<<4 on 16B chunks.
  // V rows 128B (bank-period 0 mod 128B) -> XOR (row&7)<<4. Both minimum-conflict.
#define STAGE(T, BF)                                                           \
  {                                                                            \
    _Pragma("unroll")                                                          \
    for (int rr = 0; rr < 4; ++rr) {                                           \
      int slot = rr * 512 + tid;                                               \
      int krow = slot >> 5;                                                    \
      int dby = ((slot & 31) << 4) ^ ((krow & 7) << 4);                        \
      const char* g = Kbase + (size_t)((T) * 64 + krow) * 512 + dby;           \
      __builtin_amdgcn_global_load_lds(                                        \
          (const __attribute__((address_space(1))) void*)g,                    \
          (__attribute__((address_space(3))) void*)(Ksm[BF] + slot * 16), 16, 0, 0); \
    }                                                                          \
    _Pragma("unroll")                                                          \
    for (int rr = 0; rr < 4; ++rr) {                                           \
      int slot = rr * 512 + tid;                                               \
      int vrow = slot >> 3;                                                    \
      int dby = ((slot & 7) << 4) ^ ((vrow & 7) << 4);                         \
      const char* g = Vbase + (size_t)vrow * 8192 + (T) * 128 + dby;           \
      __builtin_amdgcn_global_load_lds(                                        \
          (const __attribute__((address_space(1))) void*)g,                    \
          (__attribute__((address_space(3))) void*)(Vsm[BF] + slot * 16), 16, 0, 0); \
    }                                                                          \
  }

  int kswz = (ln & 7) << 4;
  int vswz = (ln & 7) << 4;
  int hi16 = hi * 16;

  // softmax on SA -> updates m_, l_, O-rescale (defer-max), emits PA0/PA1
#define SOFTMAX(SA, PA0, PA1)                                                  \
  {                                                                            \
    float pm = fmaxf(                                                          \
        fmaxf(fmaxf(fmaxf(SA[0], SA[1]), fmaxf(SA[2], SA[3])),                 \
              fmaxf(fmaxf(SA[4], SA[5]), fmaxf(SA[6], SA[7]))),                \
        fmaxf(fmaxf(fmaxf(SA[8], SA[9]), fmaxf(SA[10], SA[11])),               \
              fmaxf(fmaxf(SA[12], SA[13]), fmaxf(SA[14], SA[15]))));           \
    pm = fmaxf(pm, __shfl_xor(pm, 32));                                        \
    if (!__all(pm <= m_ + 8.0f)) {                                             \
      float mn = fmaxf(m_, pm);                                                \
      float sc = __expf(m_ - mn);                                              \
      m_ = mn; l_ *= sc;                                                       \
      _Pragma("unroll")                                                        \
      for (int rg = 0; rg < 16; ++rg) {                                        \
        float srg = __shfl(sc, (rg & 3) + 8 * (rg >> 2) + 4 * hi);             \
        _Pragma("unroll")                                                      \
        for (int dt = 0; dt < 8; ++dt) O[dt][rg] *= srg;                       \
      }                                                                        \
    }                                                                          \
    float p_[16];                                                              \
    _Pragma("unroll")                                                          \
    for (int j = 0; j < 16; ++j) p_[j] = __expf(SA[j] - m_);                   \
    float ps = (((p_[0] + p_[1]) + (p_[2] + p_[3])) +                          \
                ((p_[4] + p_[5]) + (p_[6] + p_[7]))) +                         \
               (((p_[8] + p_[9]) + (p_[10] + p_[11])) +                        \
                ((p_[12] + p_[13]) + (p_[14] + p_[15])));                      \
    ps += __shfl_xor(ps, 32);                                                  \
    l_ += ps;                                                                  \
    {                                                                          \
      u32x2 r1 = __builtin_amdgcn_permlane32_swap(pkrtz(p_[0], p_[1]), pkrtz(p_[4], p_[5]), false, false); \
      u32x2 r2 = __builtin_amdgcn_permlane32_swap(pkrtz(p_[2], p_[3]), pkrtz(p_[6], p_[7]), false, false); \
      PA0.w[0] = r1[0]; PA0.w[1] = r2[0]; PA0.w[2] = r1[1]; PA0.w[3] = r2[1];  \
      u32x2 r3 = __builtin_amdgcn_permlane32_swap(pkrtz(p_[8], p_[9]), pkrtz(p_[12], p_[13]), false, false); \
      u32x2 r4 = __builtin_amdgcn_permlane32_swap(pkrtz(p_[10], p_[11]), pkrtz(p_[14], p_[15]), false, false); \
      PA1.w[0] = r3[0]; PA1.w[1] = r4[0]; PA1.w[2] = r3[1]; PA1.w[3] = r4[1];  \
    }                                                                          \
  }

  STAGE(0, 0);

  for (int t = 0; t < 16; ++t) {
    __builtin_amdgcn_s_barrier();            // all reads of buffer (t+1)&1 done
    if (t < 15) {
      STAGE(t + 1, (t + 1) & 1);
      asm volatile("s_waitcnt vmcnt(8)" ::: "memory");   // stage(t) landed
    } else {
      asm volatile("s_waitcnt vmcnt(0)" ::: "memory");
    }
    __builtin_amdgcn_sched_barrier(0);
    __builtin_amdgcn_s_barrier();            // stage(t) visible to all waves

    const char* Kc = Ksm[t & 1];
    const char* Vc = Vsm[t & 1];

    // ---- half 0: QK ----
    f32x16 sA = (f32x16)0.0f;
    __builtin_amdgcn_s_setprio(1);
    #pragma unroll
    for (int ks = 0; ks < 16; ++ks) {
      f16x8 kf = *(const f16x8*)(Kc + ln * 512 + ((ks * 32 + hi16) ^ kswz));
      sA = __builtin_amdgcn_mfma_f32_32x32x16_f16(kf, qf[ks], sA, 0, 0, 0);
    }
    __builtin_amdgcn_s_setprio(0);
    PAu paA0, paA1;
    SOFTMAX(sA, paA0, paA1);

    // ---- half 1: QK || PV(half 0) ----
    f32x16 sB = (f32x16)0.0f;
    __builtin_amdgcn_s_setprio(1);
    #pragma unroll
    for (int ks = 0; ks < 16; ++ks) {
      f16x8 kf = *(const f16x8*)(Kc + (32 + ln) * 512 + ((ks * 32 + hi16) ^ kswz));
      sB = __builtin_amdgcn_mfma_f32_32x32x16_f16(kf, qf[ks], sB, 0, 0, 0);
      int dt = ks >> 1, k2 = ks & 1;
      f16x8 vf = *(const f16x8*)(Vc + (dt * 32 + ln) * 128 + ((k2 * 32 + hi16) ^ vswz));
      O[dt] = __builtin_amdgcn_mfma_f32_32x32x16_f16(k2 ? paA1.v : paA0.v, vf, O[dt], 0, 0, 0);
    }
    __builtin_amdgcn_s_setprio(0);
    PAu paB0, paB1;
    SOFTMAX(sB, paB0, paB1);

    // ---- PV(half 1) ----
    __builtin_amdgcn_s_setprio(1);
    #pragma unroll
    for (int ks = 0; ks < 16; ++ks) {
      int dt = ks >> 1, k2 = ks & 1;
      f16x8 vf = *(const f16x8*)(Vc + (dt * 32 + ln) * 128 + ((64 + k2 * 32 + hi16) ^ vswz));
      O[dt] = __builtin_amdgcn_mfma_f32_32x32x16_f16(k2 ? paB1.v : paB0.v, vf, O[dt], 0, 0, 0);
    }
    __builtin_amdgcn_s_setprio(0);
  }

  // epilogue: store NORMALIZED O (f16-safe), plus (m,l) per q-row
  float invl = 1.0f / l_;
  #pragma unroll
  for (int rg = 0; rg < 16; ++rg) {
    int qr = (rg & 3) + 8 * (rg >> 2) + 4 * hi;
    float iv = __shfl(invl, qr);
    size_t row = (size_t)kq * 16384 + batch * 4096 + q0 + qr;
    #pragma unroll
    for (int dt = 0; dt < 8; ++dt)
      Opart[row * 256 + dt * 32 + ln] = (f16)(O[dt][rg] * iv);
  }
  if (hi == 0) {
    size_t grow = (size_t)kq * 16384 + batch * 4096 + q0 + ln;
    Ml[grow * 2] = m_;
    Ml[grow * 2 + 1] = l_;
  }
#undef STAGE
#undef SOFTMAX
}

// ---- Kernel D: split-K merge (Opart normalized; weight = exp(m-M)*l) ----
__global__ __launch_bounds__(256) void merge_kernel(
    const f16* __restrict__ Opart, const float* __restrict__ Ml,
    float* __restrict__ out) {
  int gid = blockIdx.x * 256 + threadIdx.x;
  int row = gid >> 5, d0 = (gid & 31) * 8;
  float m[4], l[4];
  #pragma unroll
  for (int p = 0; p < 4; ++p) {
    m[p] = Ml[((size_t)p * 16384 + row) * 2];
    l[p] = Ml[((size_t)p * 16384 + row) * 2 + 1];
  }
  float M = fmaxf(fmaxf(m[0], m[1]), fmaxf(m[2], m[3]));
  float wl[4], L = 0.f;
  #pragma unroll
  for (int p = 0; p < 4; ++p) { wl[p] = __expf(m[p] - M) * l[p]; L += wl[p]; }
  float o[8] = {0.f, 0.f, 0.f, 0.f, 0.f, 0.f, 0.f, 0.f};
  #pragma unroll
  for (int p = 0; p < 4; ++p) {
    f16x8 v = *(const f16x8*)(Opart + ((size_t)p * 16384 + row) * 256 + d0);
    #pragma unroll
    for (int j = 0; j < 8; ++j) o[j] += wl[p] * (float)v[j];
  }
  float invL = 1.0f / L;
  float4 o0 = {o[0] * invL, o[1] * invL, o[2] * invL, o[3] * invL};
  float4 o1 = {o[4] * invL, o[5] * invL, o[6] * invL, o[7] * invL};
  *(float4*)(out + (size_t)row * 256 + d0) = o0;
  *(float4*)(out + (size_t)row * 256 + d0 + 4) = o1;
}

extern "C" void kernel_launch(void* const* d_in, const int* in_sizes, int n_in,
                              void* d_out, int out_size, void* d_ws, size_t ws_size,
                              hipStream_t stream) {
  const float* x  = (const float*)d_in[0];
  const float* Wq = (const float*)d_in[1];
  const float* bq = (const float*)d_in[2];
  const float* Wk = (const float*)d_in[3];
  const float* bk = (const float*)d_in[4];
  const float* Wv = (const float*)d_in[5];
  const float* bv = (const float*)d_in[6];
  float* out = (float*)d_out;

  u16* Wh = (u16*)d_ws;
  u16* Wl = Wh + 3 * 65536;
  f16* Qf = (f16*)(Wl + 3 * 65536);
  f16* Kf = Qf + (size_t)16384 * 256;
  f16* Vt = Kf + (size_t)16384 * 256;
  f16* Opart = Vt + (size_t)4 * 256 * 4096;
  float* Ml = (float*)(Opart + (size_t)4 * 16384 * 256);

  wt_kernel<<<48, 256, 0, stream>>>(Wq, Wk, Wv, Wh, Wl);
  proj_kernel<<<dim3(128, 3), 256, 0, stream>>>(x, bq, bk, bv, Wh, Wl, Qf, Kf, Vt);
  attn_kernel<<<256, 512, 0, stream>>>(Qf, Kf, Vt, Opart, Ml);
  merge_kernel<<<2048, 256, 0, stream>>>(Opart, Ml, out);
}

// Round 7
// 153.720 us; speedup vs baseline: 2.7008x; 1.0238x over previous
//
#include <hip/hip_runtime.h>
#include <stdint.h>

typedef __bf16 bf16;
typedef bf16 bf16x8 __attribute__((ext_vector_type(8)));
typedef _Float16 f16;
typedef f16 f16x8 __attribute__((ext_vector_type(8)));
typedef f16 f16x4 __attribute__((ext_vector_type(4)));
typedef float f32x4 __attribute__((ext_vector_type(4)));
typedef float f32x16 __attribute__((ext_vector_type(16)));
typedef unsigned short u16;
typedef unsigned int u32;
typedef u32 u32x2 __attribute__((ext_vector_type(2)));
typedef u16 u16x8v __attribute__((ext_vector_type(8)));

#define LOG2E 1.44269504088896340736f

__device__ __forceinline__ u16 f2bf(float f) {
  u32 u = __float_as_uint(f);
  u32 r = u + 0x7fffu + ((u >> 16) & 1u);
  return (u16)(r >> 16);
}
__device__ __forceinline__ float bf2f(u16 h) { return __uint_as_float(((u32)h) << 16); }

__device__ __forceinline__ u32 pkrtz(float a, float b) {
  auto r = __builtin_amdgcn_cvt_pkrtz(a, b);   // f16x2: a->[15:0], b->[31:16]
  u32 u; __builtin_memcpy(&u, &r, 4);
  return u;
}
// cross-32 reduce helpers via permlane32_swap (VALU, no LDS pipe):
// out0 = {lo:v_lo, hi:v_lo}, out1 = {lo:v_hi, hi:v_hi} -> combine(out0,out1) = full
__device__ __forceinline__ float xmax32(float v) {
  u32x2 r = __builtin_amdgcn_permlane32_swap(__float_as_uint(v), __float_as_uint(v), false, false);
  return fmaxf(__uint_as_float(r[0]), __uint_as_float(r[1]));
}
__device__ __forceinline__ float xsum32(float v) {
  u32x2 r = __builtin_amdgcn_permlane32_swap(__float_as_uint(v), __float_as_uint(v), false, false);
  return __uint_as_float(r[0]) + __uint_as_float(r[1]);
}

union ABu { u16x8v u; bf16x8 b; };
union PAu { u32 w[4]; f16x8 v; };

// ---- Kernel A: Wh/Wl[w][out][in] = split-bf16 of W_w[in][out] ----
__global__ void wt_kernel(const float* __restrict__ Wq, const float* __restrict__ Wk,
                          const float* __restrict__ Wv, u16* __restrict__ Wh,
                          u16* __restrict__ Wl) {
  int w = blockIdx.x >> 4;
  int chunk = blockIdx.x & 15;
  const float* W = (w == 0) ? Wq : (w == 1) ? Wk : Wv;
  int t = threadIdx.x;
  int o = chunk * 16 + (t & 15);
  int i0 = (t >> 4) * 16;
  u16x8v h0, h1, l0, l1;
  #pragma unroll
  for (int ii = 0; ii < 8; ++ii) {
    float v0 = W[(size_t)(i0 + ii) * 256 + o];
    u16 h = f2bf(v0); h0[ii] = h; l0[ii] = f2bf(v0 - bf2f(h));
    float v1 = W[(size_t)(i0 + 8 + ii) * 256 + o];
    h = f2bf(v1); h1[ii] = h; l1[ii] = f2bf(v1 - bf2f(h));
  }
  size_t base = (size_t)w * 65536 + (size_t)o * 256 + i0;
  *(u16x8v*)(Wh + base) = h0; *(u16x8v*)(Wh + base + 8) = h1;
  *(u16x8v*)(Wl + base) = l0; *(u16x8v*)(Wl + base + 8) = l1;
}

// ---- Kernel B: QKV projection (fp32-exact 3-pass bf16), W slices staged in LDS ----
// Q output is pre-scaled by log2(e) so attention softmax runs in exp2 domain.
__global__ __launch_bounds__(256, 2) void proj_kernel(
    const float* __restrict__ x, const float* __restrict__ bq,
    const float* __restrict__ bk, const float* __restrict__ bv,
    const u16* __restrict__ Wh, const u16* __restrict__ Wl,
    f16* __restrict__ Qf, f16* __restrict__ Kf, f16* __restrict__ Vt) {
  __shared__ __align__(16) char Whs[16384];   // [256 out-rows][32 in] bf16, swizzled
  __shared__ __align__(16) char Wls[16384];

  int m = blockIdx.x, w = blockIdx.y;
  int tid = threadIdx.x, lane = tid & 63, wv = tid >> 6;
  int r = lane & 15, c = lane >> 4;
  int row0 = m * 128 + wv * 32;
  const char* Whw = (const char*)(Wh + (size_t)w * 65536);
  const char* Wlw = (const char*)(Wl + (size_t)w * 65536);
  const float* bias = (w == 0) ? bq : (w == 1) ? bk : bv;

  f32x4 acc[2][16];
  #pragma unroll
  for (int g = 0; g < 2; ++g)
    #pragma unroll
    for (int n = 0; n < 16; ++n) acc[g][n] = (f32x4)0.0f;

  for (int ks = 0; ks < 8; ++ks) {
    if (ks) __syncthreads();
    #pragma unroll
    for (int ss = 0; ss < 4; ++ss) {
      int slot = ss * 256 + tid;
      int row = slot >> 2, c4 = slot & 3;
      int dby = (c4 << 4) ^ (((row >> 1) & 3) << 4);
      const char* gh = Whw + (size_t)row * 512 + ks * 64 + dby;
      const char* gl = Wlw + (size_t)row * 512 + ks * 64 + dby;
      __builtin_amdgcn_global_load_lds(
          (const __attribute__((address_space(1))) void*)gh,
          (__attribute__((address_space(3))) void*)(Whs + slot * 16), 16, 0, 0);
      __builtin_amdgcn_global_load_lds(
          (const __attribute__((address_space(1))) void*)gl,
          (__attribute__((address_space(3))) void*)(Wls + slot * 16), 16, 0, 0);
    }
    __syncthreads();

    ABu ah[2], al[2];
    #pragma unroll
    for (int g = 0; g < 2; ++g) {
      const float* xrow = x + (size_t)(row0 + g * 16 + r) * 256 + ks * 32 + c * 8;
      float4 a0 = *(const float4*)(xrow);
      float4 a1 = *(const float4*)(xrow + 4);
      float xv[8] = {a0.x, a0.y, a0.z, a0.w, a1.x, a1.y, a1.z, a1.w};
      #pragma unroll
      for (int j = 0; j < 8; ++j) {
        u16 h = f2bf(xv[j]);
        ah[g].u[j] = h;
        al[g].u[j] = f2bf(xv[j] - bf2f(h));
      }
    }
    #pragma unroll
    for (int n = 0; n < 16; ++n) {
      int wrow = n * 16 + r;
      int wof = (c * 16) ^ (((wrow >> 1) & 3) << 4);
      bf16x8 whf = *(const bf16x8*)(Whs + wrow * 64 + wof);
      bf16x8 wlf = *(const bf16x8*)(Wls + wrow * 64 + wof);
      #pragma unroll
      for (int g = 0; g < 2; ++g) {
        acc[g][n] = __builtin_amdgcn_mfma_f32_16x16x32_bf16(ah[g].b, whf, acc[g][n], 0, 0, 0);
        acc[g][n] = __builtin_amdgcn_mfma_f32_16x16x32_bf16(al[g].b, whf, acc[g][n], 0, 0, 0);
        acc[g][n] = __builtin_amdgcn_mfma_f32_16x16x32_bf16(ah[g].b, wlf, acc[g][n], 0, 0, 0);
      }
    }
  }

  if (w < 2) {
    f16* outp = (w == 0) ? Qf : Kf;
    float osc = (w == 0) ? LOG2E : 1.0f;   // exp2-domain scores
    #pragma unroll
    for (int g = 0; g < 2; ++g)
      #pragma unroll
      for (int n = 0; n < 16; ++n) {
        int col = n * 16 + r;
        float bb = bias[col];
        #pragma unroll
        for (int i = 0; i < 4; ++i) {
          float v = fmaxf(acc[g][n][i] + bb, 0.0f) * osc;
          outp[(size_t)(row0 + g * 16 + c * 4 + i) * 256 + col] = (f16)v;
        }
      }
  } else {
    #pragma unroll
    for (int g = 0; g < 2; ++g) {
      int grow = row0 + g * 16 + c * 4;
      int b = grow >> 12, s0 = grow & 4095;
      #pragma unroll
      for (int n = 0; n < 16; ++n) {
        int d = n * 16 + r;
        float bb = bias[d];
        f16x4 pk;
        #pragma unroll
        for (int i = 0; i < 4; ++i) pk[i] = (f16)(acc[g][n][i] + bb);
        *(f16x4*)(Vt + (size_t)(b * 256 + d) * 4096 + s0) = pk;
      }
    }
  }
}

// ---- Kernel C: flash attention ----
// 256 blocks x 8 waves, 32 q-rows/wave, KVBLK=64, splitK=4, K/V dbuf (128KB LDS).
// Wave-parity phase stagger: even waves process key-half A=[0,32) first, odd
// waves half B=[32,64) first -> one parity runs softmax (VALU) while the other
// runs MFMA, breaking barrier-lockstep on the 2-wave/SIMD occupancy.
__global__ __launch_bounds__(512, 2) void attn_kernel(
    const f16* __restrict__ Qf, const f16* __restrict__ Kf,
    const f16* __restrict__ Vt, f16* __restrict__ Opart, float* __restrict__ Ml) {
  __shared__ __align__(16) char Ksm[2][32768];   // [64 keys][256 d] f16, swizzled
  __shared__ __align__(16) char Vsm[2][32768];   // [256 d][64 keys] f16, swizzled

  int bid = blockIdx.x;
  int xcd = bid & 7;
  int batch = xcd >> 1;
  int kq = ((xcd & 1) << 1) | ((bid >> 3) & 1);
  int qtl = bid >> 4;
  int tid = threadIdx.x, lane = tid & 63, wv = tid >> 6;
  int ln = lane & 31, hi = lane >> 5;
  int q0 = qtl * 256 + wv * 32;
  int kv0 = kq * 1024;
  int par = wv & 1;

  f16x8 qf[16];
  {
    const f16* qp = Qf + ((size_t)(batch * 4096 + q0 + ln)) * 256 + hi * 8;
    #pragma unroll
    for (int ks = 0; ks < 16; ++ks) qf[ks] = *(const f16x8*)(qp + ks * 16);
  }

  f32x16 O[8];
  #pragma unroll
  for (int dt = 0; dt < 8; ++dt) O[dt] = (f32x16)0.0f;
  float m_ = -1.0e30f, l_ = 0.0f;

  const char* Kbase = (const char*)(Kf + ((size_t)(batch * 4096 + kv0)) * 256);
  const char* Vbase = (const char*)(Vt + (size_t)batch * 1048576 + kv0);

#define STAGE(T, BF)                                                           \
  {                                                                            \
    _Pragma("unroll")                                                          \
    for (int rr = 0; rr < 4; ++rr) {                                           \
      int slot = rr * 512 + tid;                                               \
      int krow = slot >> 5;                                                    \
      int dby = ((slot & 31) << 4) ^ ((krow & 7) << 4);                        \
      const char* g = Kbase + (size_t)((T) * 64 + krow) * 512 + dby;           \
      __builtin_amdgcn_global_load_lds(                                        \
          (const __attribute__((address_space(1))) void*)g,                    \
          (__attribute__((address_space(3))) void*)(Ksm[BF] + slot * 16), 16, 0, 0); \
    }                                                                          \
    _Pragma("unroll")                                                          \
    for (int rr = 0; rr < 4; ++rr) {                                           \
      int slot = rr * 512 + tid;                                               \
      int vrow = slot >> 3;                                                    \
      int dby = ((slot & 7) << 4) ^ ((vrow & 7) << 4);                         \
      const char* g = Vbase + (size_t)vrow * 8192 + (T) * 128 + dby;           \
      __builtin_amdgcn_global_load_lds(                                        \
          (const __attribute__((address_space(1))) void*)g,                    \
          (__attribute__((address_space(3))) void*)(Vsm[BF] + slot * 16), 16, 0, 0); \
    }                                                                          \
  }

  int kswz = (ln & 7) << 4;
  int vswz = (ln & 7) << 4;
  int hi16 = hi * 16;
  int kbA = par * 32;          // even waves: keys [0,32) first; odd: [32,64)
  int kbB = 32 - kbA;

  // exp2-domain softmax (scores pre-scaled by log2e via Q)
#define SOFTMAX(SA, PA0, PA1)                                                  \
  {                                                                            \
    float pm = fmaxf(                                                          \
        fmaxf(fmaxf(fmaxf(SA[0], SA[1]), fmaxf(SA[2], SA[3])),                 \
              fmaxf(fmaxf(SA[4], SA[5]), fmaxf(SA[6], SA[7]))),                \
        fmaxf(fmaxf(fmaxf(SA[8], SA[9]), fmaxf(SA[10], SA[11])),               \
              fmaxf(fmaxf(SA[12], SA[13]), fmaxf(SA[14], SA[15]))));           \
    pm = xmax32(pm);                                                           \
    if (!__all(pm <= m_ + 11.5416f)) {    /* defer-max, THR=8 in e-domain */   \
      float mn = fmaxf(m_, pm);                                                \
      float sc = exp2f(m_ - mn);                                               \
      m_ = mn; l_ *= sc;                                                       \
      _Pragma("unroll")                                                        \
      for (int rg = 0; rg < 16; ++rg) {                                        \
        float srg = __shfl(sc, (rg & 3) + 8 * (rg >> 2) + 4 * hi);             \
        _Pragma("unroll")                                                      \
        for (int dt = 0; dt < 8; ++dt) O[dt][rg] *= srg;                       \
      }                                                                        \
    }                                                                          \
    float p_[16];                                                              \
    _Pragma("unroll")                                                          \
    for (int j = 0; j < 16; ++j) p_[j] = exp2f(SA[j] - m_);                    \
    float ps = (((p_[0] + p_[1]) + (p_[2] + p_[3])) +                          \
                ((p_[4] + p_[5]) + (p_[6] + p_[7]))) +                         \
               (((p_[8] + p_[9]) + (p_[10] + p_[11])) +                        \
                ((p_[12] + p_[13]) + (p_[14] + p_[15])));                      \
    l_ += xsum32(ps);                                                          \
    {                                                                          \
      u32x2 r1 = __builtin_amdgcn_permlane32_swap(pkrtz(p_[0], p_[1]), pkrtz(p_[4], p_[5]), false, false); \
      u32x2 r2 = __builtin_amdgcn_permlane32_swap(pkrtz(p_[2], p_[3]), pkrtz(p_[6], p_[7]), false, false); \
      PA0.w[0] = r1[0]; PA0.w[1] = r2[0]; PA0.w[2] = r1[1]; PA0.w[3] = r2[1];  \
      u32x2 r3 = __builtin_amdgcn_permlane32_swap(pkrtz(p_[8], p_[9]), pkrtz(p_[12], p_[13]), false, false); \
      u32x2 r4 = __builtin_amdgcn_permlane32_swap(pkrtz(p_[10], p_[11]), pkrtz(p_[14], p_[15]), false, false); \
      PA1.w[0] = r3[0]; PA1.w[1] = r4[0]; PA1.w[2] = r3[1]; PA1.w[3] = r4[1];  \
    }                                                                          \
  }

  STAGE(0, 0);

  for (int t = 0; t < 16; ++t) {
    __builtin_amdgcn_s_barrier();
    if (t < 15) {
      STAGE(t + 1, (t + 1) & 1);
      asm volatile("s_waitcnt vmcnt(8)" ::: "memory");
    } else {
      asm volatile("s_waitcnt vmcnt(0)" ::: "memory");
    }
    __builtin_amdgcn_sched_barrier(0);
    __builtin_amdgcn_s_barrier();

    const char* Kc = Ksm[t & 1];
    const char* Vc = Vsm[t & 1];
    const char* KcA = Kc + kbA * 512;
    const char* KcB = Kc + kbB * 512;
    int vbA = kbA * 2, vbB = kbB * 2;   // byte offset within 128B V row

    // ---- phase 1: QK(half A) ----
    f32x16 sA = (f32x16)0.0f;
    __builtin_amdgcn_s_setprio(1);
    #pragma unroll
    for (int ks = 0; ks < 16; ++ks) {
      f16x8 kf = *(const f16x8*)(KcA + ln * 512 + ((ks * 32 + hi16) ^ kswz));
      sA = __builtin_amdgcn_mfma_f32_32x32x16_f16(kf, qf[ks], sA, 0, 0, 0);
    }
    __builtin_amdgcn_s_setprio(0);
    PAu paA0, paA1;
    SOFTMAX(sA, paA0, paA1);

    // ---- phase 2: QK(half B) || PV(half A) ----
    f32x16 sB = (f32x16)0.0f;
    __builtin_amdgcn_s_setprio(1);
    #pragma unroll
    for (int ks = 0; ks < 16; ++ks) {
      f16x8 kf = *(const f16x8*)(KcB + ln * 512 + ((ks * 32 + hi16) ^ kswz));
      sB = __builtin_amdgcn_mfma_f32_32x32x16_f16(kf, qf[ks], sB, 0, 0, 0);
      int dt = ks >> 1, k2 = ks & 1;
      f16x8 vf = *(const f16x8*)(Vc + (dt * 32 + ln) * 128 + ((vbA + k2 * 32 + hi16) ^ vswz));
      O[dt] = __builtin_amdgcn_mfma_f32_32x32x16_f16(k2 ? paA1.v : paA0.v, vf, O[dt], 0, 0, 0);
    }
    __builtin_amdgcn_s_setprio(0);
    PAu paB0, paB1;
    SOFTMAX(sB, paB0, paB1);

    // ---- phase 3: PV(half B) ----
    __builtin_amdgcn_s_setprio(1);
    #pragma unroll
    for (int ks = 0; ks < 16; ++ks) {
      int dt = ks >> 1, k2 = ks & 1;
      f16x8 vf = *(const f16x8*)(Vc + (dt * 32 + ln) * 128 + ((vbB + k2 * 32 + hi16) ^ vswz));
      O[dt] = __builtin_amdgcn_mfma_f32_32x32x16_f16(k2 ? paB1.v : paB0.v, vf, O[dt], 0, 0, 0);
    }
    __builtin_amdgcn_s_setprio(0);
  }

  // epilogue: store NORMALIZED O (f16-safe), plus (m,l) per q-row
  float invl = 1.0f / l_;
  #pragma unroll
  for (int rg = 0; rg < 16; ++rg) {
    int qr = (rg & 3) + 8 * (rg >> 2) + 4 * hi;
    float iv = __shfl(invl, qr);
    size_t row = (size_t)kq * 16384 + batch * 4096 + q0 + qr;
    #pragma unroll
    for (int dt = 0; dt < 8; ++dt)
      Opart[row * 256 + dt * 32 + ln] = (f16)(O[dt][rg] * iv);
  }
  if (hi == 0) {
    size_t grow = (size_t)kq * 16384 + batch * 4096 + q0 + ln;
    Ml[grow * 2] = m_;
    Ml[grow * 2 + 1] = l_;
  }
#undef STAGE
#undef SOFTMAX
}

// ---- Kernel D: split-K merge (m stored in log2 domain -> exp2 weights) ----
__global__ __launch_bounds__(256) void merge_kernel(
    const f16* __restrict__ Opart, const float* __restrict__ Ml,
    float* __restrict__ out) {
  int gid = blockIdx.x * 256 + threadIdx.x;
  int row = gid >> 5, d0 = (gid & 31) * 8;
  float m[4], l[4];
  #pragma unroll
  for (int p = 0; p < 4; ++p) {
    m[p] = Ml[((size_t)p * 16384 + row) * 2];
    l[p] = Ml[((size_t)p * 16384 + row) * 2 + 1];
  }
  float M = fmaxf(fmaxf(m[0], m[1]), fmaxf(m[2], m[3]));
  float wl[4], L = 0.f;
  #pragma unroll
  for (int p = 0; p < 4; ++p) { wl[p] = exp2f(m[p] - M) * l[p]; L += wl[p]; }
  float o[8] = {0.f, 0.f, 0.f, 0.f, 0.f, 0.f, 0.f, 0.f};
  #pragma unroll
  for (int p = 0; p < 4; ++p) {
    f16x8 v = *(const f16x8*)(Opart + ((size_t)p * 16384 + row) * 256 + d0);
    #pragma unroll
    for (int j = 0; j < 8; ++j) o[j] += wl[p] * (float)v[j];
  }
  float invL = 1.0f / L;
  float4 o0 = {o[0] * invL, o[1] * invL, o[2] * invL, o[3] * invL};
  float4 o1 = {o[4] * invL, o[5] * invL, o[6] * invL, o[7] * invL};
  *(float4*)(out + (size_t)row * 256 + d0) = o0;
  *(float4*)(out + (size_t)row * 256 + d0 + 4) = o1;
}

extern "C" void kernel_launch(void* const* d_in, const int* in_sizes, int n_in,
                              void* d_out, int out_size, void* d_ws, size_t ws_size,
                              hipStream_t stream) {
  const float* x  = (const float*)d_in[0];
  const float* Wq = (const float*)d_in[1];
  const float* bq = (const float*)d_in[2];
  const float* Wk = (const float*)d_in[3];
  const float* bk = (const float*)d_in[4];
  const float* Wv = (const float*)d_in[5];
  const float* bv = (const float*)d_in[6];
  float* out = (float*)d_out;

  u16* Wh = (u16*)d_ws;
  u16* Wl = Wh + 3 * 65536;
  f16* Qf = (f16*)(Wl + 3 * 65536);
  f16* Kf = Qf + (size_t)16384 * 256;
  f16* Vt = Kf + (size_t)16384 * 256;
  f16* Opart = Vt + (size_t)4 * 256 * 4096;
  float* Ml = (float*)(Opart + (size_t)4 * 16384 * 256);

  wt_kernel<<<48, 256, 0, stream>>>(Wq, Wk, Wv, Wh, Wl);
  proj_kernel<<<dim3(128, 3), 256, 0, stream>>>(x, bq, bk, bv, Wh, Wl, Qf, Kf, Vt);
  attn_kernel<<<256, 512, 0, stream>>>(Qf, Kf, Vt, Opart, Ml);
  merge_kernel<<<2048, 256, 0, stream>>>(Opart, Ml, out);
}